// Round 1
// 528.107 us; speedup vs baseline: 1.0004x; 1.0004x over previous
//
#include <hip/hip_runtime.h>

#define CD 768
#define NHEAD 12
#define DH 64
#define BSZ 2
#define NM_ 4096
#define NX_ 16384
#define EPSF 1e-6f
#define KSTR 1536   // ushort stride of in-place bf16 rows inside an fp32 buffer
#define KVCH 32     // split-K chunks for kv partials

using bf16x8 = __attribute__((ext_vector_type(8))) short;
using f32x4  = __attribute__((ext_vector_type(4))) float;

__device__ inline unsigned short bf16r(float f) {
  union { float f; unsigned u; } un; un.f = f;
  unsigned u = un.u;
  u += 0x7fffu + ((u >> 16) & 1u);
  return (unsigned short)(u >> 16);
}
// cast-based conversion: compiler emits v_cvt_pk_bf16_f32 (RNE, bit-identical to bf16r)
__device__ inline unsigned short bf16c(float f) {
  union { __bf16 h; unsigned short u; } x; x.h = (__bf16)f; return x.u;
}
__device__ inline float b2f(unsigned short u) {
  union { unsigned u; float f; } x; x.u = ((unsigned)u) << 16; return x.f;
}
__device__ inline float asf(unsigned u) {
  union { unsigned u; float f; } x; x.u = u; return x.f;
}
// async global->LDS, 16B per lane; LDS dest = wave-uniform base + lane*16
__device__ inline void gl2lds16(const void* g, void* l) {
  __builtin_amdgcn_global_load_lds(
      (const __attribute__((address_space(1))) void*)g,
      (__attribute__((address_space(3))) void*)l, 16, 0, 0);
}

// ---- prep: 4 weight matrices fp32->bf16 + softplus(scale), ONE dispatch ----
__global__ __launch_bounds__(256) void prep_k(const float* __restrict__ w0, const float* __restrict__ w1,
                                              const float* __restrict__ w2, const float* __restrict__ w3,
                                              const float* __restrict__ scale,
                                              unsigned short* __restrict__ o0, unsigned short* __restrict__ o1,
                                              unsigned short* __restrict__ o2, unsigned short* __restrict__ o3,
                                              float* __restrict__ sp) {
  int bx = blockIdx.x;
  if (bx < 2304) {                    // 4 matrices x 576 blocks x 256 float4
    int m = bx / 576;
    int i = (bx % 576) * 256 + threadIdx.x;
    const float* w = m == 0 ? w0 : m == 1 ? w1 : m == 2 ? w2 : w3;
    unsigned short* o = m == 0 ? o0 : m == 1 ? o1 : m == 2 ? o2 : o3;
    float4 v = ((const float4*)w)[i];
    ushort4 u; u.x = bf16r(v.x); u.y = bf16r(v.y); u.z = bf16r(v.z); u.w = bf16r(v.w);
    ((ushort4*)o)[i] = u;
  } else {
    int i = (bx - 2304) * 256 + threadIdx.x;
    if (i < CD) sp[i] = log1pf(expf(scale[i]));
  }
}

// ------- 128x128-tile GEMM: C[M,N] = A[M,K] @ B[N,K]^T (+bias) --------------
// AFP32: A is fp32, converted to bf16 during LDS staging (conflict-free map).
// 1D grid, XCD-swizzled: blocks sharing an A row-panel (same m, all n) run
// adjacently on the SAME XCD so A re-reads hit that XCD's L2 instead of L3.
template<int AFP32, int OUTBF>
__global__ __launch_bounds__(256) void gemm128(const void* __restrict__ Av,
                                               const unsigned short* __restrict__ B,
                                               void* __restrict__ Cv,
                                               const float* __restrict__ bias,
                                               int M, int N, int K) {
  __shared__ __align__(16) unsigned short As[128 * 32];
  __shared__ __align__(16) unsigned short Bs[128 * 32];
  const int nwg = gridDim.x;
  int bid = blockIdx.x;
  int lid = (nwg & 7) ? bid : ((bid & 7) * (nwg >> 3) + (bid >> 3));
  const int nby = N >> 7;
  const int m0 = (lid / nby) * 128, n0 = (lid % nby) * 128;   // n-fast within XCD chunk
  const int tid = threadIdx.x, wave = tid >> 6, lane = tid & 63;
  const int quad = lane >> 4, l16 = lane & 15;
  const int wm = (wave >> 1) * 64, wn = (wave & 1) * 64;
  const int srow = lane >> 2, scol = (lane & 3) * 8;  // gl2lds: 16 rows/chunk, 4 lanes/row
  const int ar = tid >> 2, ac = (tid & 3) * 8;        // fp32-A staging map
  f32x4 acc[4][4] = {};
  for (int k0 = 0; k0 < K; k0 += 32) {
    float4 f0, f1, f2, f3;
    if (AFP32) {
      const float* Af = (const float*)Av;
      f0 = *(const float4*)(Af + (size_t)(m0 + ar) * K + k0 + ac);
      f1 = *(const float4*)(Af + (size_t)(m0 + ar) * K + k0 + ac + 4);
      f2 = *(const float4*)(Af + (size_t)(m0 + ar + 64) * K + k0 + ac);
      f3 = *(const float4*)(Af + (size_t)(m0 + ar + 64) * K + k0 + ac + 4);
    }
    __syncthreads();
    if (AFP32) {
      ushort4 u0, u1, u2, u3;
      u0.x = bf16c(f0.x); u0.y = bf16c(f0.y); u0.z = bf16c(f0.z); u0.w = bf16c(f0.w);
      u1.x = bf16c(f1.x); u1.y = bf16c(f1.y); u1.z = bf16c(f1.z); u1.w = bf16c(f1.w);
      u2.x = bf16c(f2.x); u2.y = bf16c(f2.y); u2.z = bf16c(f2.z); u2.w = bf16c(f2.w);
      u3.x = bf16c(f3.x); u3.y = bf16c(f3.y); u3.z = bf16c(f3.z); u3.w = bf16c(f3.w);
      *(ushort4*)(As + ar * 32 + ac) = u0;
      *(ushort4*)(As + ar * 32 + ac + 4) = u1;
      *(ushort4*)(As + (ar + 64) * 32 + ac) = u2;
      *(ushort4*)(As + (ar + 64) * 32 + ac + 4) = u3;
    } else {
      const unsigned short* A = (const unsigned short*)Av;
      #pragma unroll
      for (int c2 = 0; c2 < 2; ++c2) {
        int ch = wave * 2 + c2;
        gl2lds16(A + (size_t)(m0 + ch * 16 + srow) * K + k0 + scol, (void*)(As + ch * 512));
      }
    }
    #pragma unroll
    for (int c2 = 0; c2 < 2; ++c2) {
      int ch = wave * 2 + c2;
      gl2lds16(B + (size_t)(n0 + ch * 16 + srow) * K + k0 + scol, (void*)(Bs + ch * 512));
    }
    __syncthreads();
    bf16x8 a[4], bb[4];
    #pragma unroll
    for (int t = 0; t < 4; ++t) {
      a[t]  = *(const bf16x8*)(As + (wm + t * 16 + l16) * 32 + quad * 8);
      bb[t] = *(const bf16x8*)(Bs + (wn + t * 16 + l16) * 32 + quad * 8);
    }
    #pragma unroll
    for (int tm = 0; tm < 4; ++tm)
      #pragma unroll
      for (int tn = 0; tn < 4; ++tn)
        acc[tm][tn] = __builtin_amdgcn_mfma_f32_16x16x32_bf16(a[tm], bb[tn], acc[tm][tn], 0, 0, 0);
  }
  // D layout: col = lane&15, row = quad*4 + r  [m89/m91 verified]
  #pragma unroll
  for (int tm = 0; tm < 4; ++tm)
    #pragma unroll
    for (int tn = 0; tn < 4; ++tn) {
      const int col = n0 + wn + tn * 16 + l16;
      const float bv = bias ? bias[col] : 0.f;
      #pragma unroll
      for (int r = 0; r < 4; ++r) {
        const int row = m0 + wm + tm * 16 + quad * 4 + r;
        float v = acc[tm][tn][r] + bv;
        if (OUTBF) ((unsigned short*)Cv)[(size_t)row * N + col] = bf16r(v);
        else       ((float*)Cv)[(size_t)row * N + col] = v;
      }
    }
}

// ------- _process: read fp32 row, write bf16 row IN-PLACE (stride KSTR) -------
__global__ __launch_bounds__(256) void process_rows(float* __restrict__ X,
                                                    const float* __restrict__ sp) {
  const int row = blockIdx.x;
  const int tid = threadIdx.x;
  float* xr = X + (size_t)row * CD;
  float tv[3];
  float n2 = 0.f, m2 = 0.f;
  #pragma unroll
  for (int i = 0; i < 3; ++i) {
    int c = tid + i * 256;
    float t = fmaxf(xr[c], 0.f) + EPSF;
    t = t / sp[c];
    tv[i] = t;
    float t2 = t * t;
    n2 += t2;
    float p = t2 * t;
    m2 += p * p;
  }
  #pragma unroll
  for (int off = 32; off; off >>= 1) {
    n2 += __shfl_down(n2, off, 64);
    m2 += __shfl_down(m2, off, 64);
  }
  __shared__ float rn[4], rm[4];
  if ((tid & 63) == 0) { rn[tid >> 6] = n2; rm[tid >> 6] = m2; }
  __syncthreads();   // also orders: all global reads done before bf16 overwrite
  float N2 = rn[0] + rn[1] + rn[2] + rn[3];
  float M2 = rm[0] + rm[1] + rm[2] + rm[3];
  float factor = sqrtf(N2 / M2);   // = ||t|| / ||t^3||
  unsigned short* xo = (unsigned short*)xr;
  #pragma unroll
  for (int i = 0; i < 3; ++i) {
    int c = tid + i * 256;
    float t = tv[i];
    xo[c] = bf16r(t * t * t * factor);
  }
}

// ---- kv partials: kvp[ch][bh][d][e] = sum_{n in chunk} k[n,d]*v[n,e] --------
// also kmp[ch][bh][d] = sum_{n in chunk} k[n,d]. No atomics.
__global__ __launch_bounds__(256) void kv_part_k(const unsigned short* __restrict__ Kp,
                                                 const unsigned short* __restrict__ Vp,
                                                 float* __restrict__ kvp,
                                                 float* __restrict__ kmp) {
  const int bh = blockIdx.x, chunk = blockIdx.y;
  const int b = bh / NHEAD, h = bh % NHEAD;
  const int n0 = chunk * 128;
  __shared__ __align__(16) unsigned short ks[128 * 72];
  __shared__ __align__(16) unsigned short vs[128 * 72];
  const int tid = threadIdx.x;
  #pragma unroll
  for (int it = 0; it < 4; ++it) {
    int g = it * 256 + tid;            // 1024 groups of 8 elements per tile
    int row = g >> 3, c8 = (g & 7) * 8;
    int4 ka = *(const int4*)(Kp + ((size_t)(n0 + row) * BSZ + b) * KSTR + h * 64 + c8);
    int4 va = *(const int4*)(Vp + ((size_t)(n0 + row) * BSZ + b) * CD + h * 64 + c8);
    *(int4*)(ks + row * 72 + c8) = ka;
    *(int4*)(vs + row * 72 + c8) = va;
  }
  __syncthreads();
  const int d0 = (tid >> 4) * 4, e0 = (tid & 15) * 4;
  float acc[4][4] = {};
  #pragma unroll 4
  for (int n = 0; n < 128; ++n) {
    ushort4 kd = *(const ushort4*)(ks + n * 72 + d0);
    ushort4 ve = *(const ushort4*)(vs + n * 72 + e0);
    float kf[4] = {b2f(kd.x), b2f(kd.y), b2f(kd.z), b2f(kd.w)};
    float vf[4] = {b2f(ve.x), b2f(ve.y), b2f(ve.z), b2f(ve.w)};
    #pragma unroll
    for (int i = 0; i < 4; ++i)
      #pragma unroll
      for (int j = 0; j < 4; ++j) acc[i][j] += kf[i] * vf[j];
  }
  float* outp = kvp + ((size_t)chunk * 24 + bh) * 4096;
  #pragma unroll
  for (int i = 0; i < 4; ++i) {
    float4 o; o.x = acc[i][0]; o.y = acc[i][1]; o.z = acc[i][2]; o.w = acc[i][3];
    *(float4*)(outp + (d0 + i) * 64 + e0) = o;
  }
  if (tid < 64) {
    float s = 0.f;
    for (int n = 0; n < 128; ++n) s += b2f(ks[n * 72 + tid]);
    kmp[((size_t)chunk * 24 + bh) * 64 + tid] = s;
  }
}

// ---- reduce partials -> kvT[bh][e][d] bf16 (+1/Nm) and km[b][c] fp32 --------
__global__ __launch_bounds__(256) void kv_reduce_k(const float* __restrict__ kvp,
                                                   const float* __restrict__ kmp,
                                                   unsigned short* __restrict__ kvT,
                                                   float* __restrict__ km) {
  const int tid = threadIdx.x;
  const int bx = blockIdx.x;
  if (bx < 24) {
    __shared__ float t[64 * 65];
    float acc[16] = {};
    const float* base = kvp + (size_t)bx * 4096 + tid * 16;
    for (int c = 0; c < KVCH; ++c) {
      const float* p = base + (size_t)c * 24 * 4096;
      #pragma unroll
      for (int i = 0; i < 4; ++i) {
        float4 v = *(const float4*)(p + i * 4);
        acc[i * 4 + 0] += v.x; acc[i * 4 + 1] += v.y; acc[i * 4 + 2] += v.z; acc[i * 4 + 3] += v.w;
      }
    }
    const int d = tid >> 2, e0 = (tid & 3) * 16;   // writes row d, cols e0..e0+15
    #pragma unroll
    for (int i = 0; i < 16; ++i) t[d * 65 + e0 + i] = acc[i] * (1.f / NM_);
    __syncthreads();
    const int e = tid >> 2, dd0 = (tid & 3) * 16;  // read col e, rows dd0..+15
    ushort4 o[4];
    #pragma unroll
    for (int i = 0; i < 16; ++i)
      ((unsigned short*)o)[i] = bf16r(t[(dd0 + i) * 65 + e]);
    unsigned short* dst = kvT + (size_t)bx * 4096 + e * 64 + dd0;
    *(ushort4*)(dst) = o[0]; *(ushort4*)(dst + 4) = o[1];
    *(ushort4*)(dst + 8) = o[2]; *(ushort4*)(dst + 12) = o[3];
  } else {
    int i = (bx - 24) * 256 + tid;                 // 6 blocks cover 1536 outputs
    if (i < 24 * 64) {
      int bhh = i >> 6, d = i & 63;
      float s = 0.f;
      for (int c = 0; c < KVCH; ++c) s += kmp[((size_t)c * 24 + bhh) * 64 + d];
      int b = bhh / NHEAD, h = bhh % NHEAD;
      km[b * CD + h * 64 + d] = s * (1.f / NM_);
    }
  }
}

// -------- depthwise 5x5 conv, LDS-tiled: block = (b,h) x 16-wide x-tile ------
__global__ __launch_bounds__(256) void dwconv_k(const unsigned short* __restrict__ Vp,
                                                const float* __restrict__ w,
                                                const float* __restrict__ bias,
                                                unsigned short* __restrict__ outp) {
  __shared__ __align__(16) unsigned ls32[16 * 20 * 32];  // ushort2-packed channels
  __shared__ float wsm[64 * 25];
  __shared__ float bsm[64];
  const int tid = threadIdx.x;
  const int bh = blockIdx.x, b = bh / NHEAD, h = bh % NHEAD;
  const int x0 = blockIdx.y * 16;
  for (int i = tid; i < 1600; i += 256) wsm[i] = w[i];
  if (tid < 64) bsm[tid] = bias[tid];
  const int lch = (tid & 7) * 8;
  #pragma unroll
  for (int it = 0; it < 10; ++it) {
    int p = it * 32 + (tid >> 3);
    int y = p / 20, xp = p % 20;
    int xx = x0 + xp - 2;
    int4 val = {0, 0, 0, 0};
    if (xx >= 0 && xx < 256)
      val = *(const int4*)(Vp + ((size_t)((y << 8) + xx) * BSZ + b) * CD + h * 64 + lch);
    *(int4*)((unsigned short*)ls32 + p * 64 + lch) = val;
  }
  __syncthreads();
  const int cp = tid & 31;        // channel pair: ch = {2cp, 2cp+1}
  const int xs = tid >> 5;        // 0..7 -> x outputs {2xs, 2xs+1}
  float wr0[25], wr1[25];
  #pragma unroll
  for (int t = 0; t < 25; ++t) { wr0[t] = wsm[(cp * 2) * 25 + t]; wr1[t] = wsm[(cp * 2 + 1) * 25 + t]; }
  const float b0 = bsm[cp * 2], b1 = bsm[cp * 2 + 1];
  for (int y = 0; y < 16; ++y) {
    float a00 = b0, a01 = b1, a10 = b0, a11 = b1;
    #pragma unroll
    for (int dy = 0; dy < 5; ++dy) {
      int yy = y + dy - 2;
      if (yy < 0 || yy >= 16) continue;
      #pragma unroll
      for (int dx = 0; dx < 5; ++dx) {
        int base = (yy * 20 + xs * 2 + dx) * 32 + cp;
        unsigned u0 = ls32[base], u1 = ls32[base + 32];
        float w0 = wr0[dy * 5 + dx], w1 = wr1[dy * 5 + dx];
        a00 += w0 * asf(u0 << 16);  a01 += w1 * asf(u0 & 0xffff0000u);
        a10 += w0 * asf(u1 << 16);  a11 += w1 * asf(u1 & 0xffff0000u);
      }
    }
    const int x = x0 + xs * 2;
    size_t o = ((size_t)((y << 8) + x) * BSZ + b) * CD + h * 64 + cp * 2;
    ushort2 s0; s0.x = bf16r(a00); s0.y = bf16r(a01);
    ushort2 s1; s1.x = bf16r(a10); s1.y = bf16r(a11);
    *(ushort2*)(outp + o) = s0;
    *(ushort2*)(outp + o + (size_t)BSZ * CD) = s1;
  }
}

// ------ attn: tmp = bf16( z * (q @ kv) + dwc ), MFMA per head, K=64 ---------
__global__ __launch_bounds__(256) void attn_mfma(const unsigned short* __restrict__ Qb,
                                                 const unsigned short* __restrict__ kvT,
                                                 const float* __restrict__ km,
                                                 const unsigned short* __restrict__ dwcb,
                                                 unsigned short* __restrict__ tmpb) {
  __shared__ __align__(16) unsigned short qs[128 * 64];
  __shared__ __align__(16) unsigned short kvs[64 * 64];
  __shared__ float kms[64];
  __shared__ float zs[128];
  const int bh = blockIdx.x, b = bh / NHEAD, h = bh % NHEAD;
  const int n0 = blockIdx.y * 128;
  const int tid = threadIdx.x, wave = tid >> 6, lane = tid & 63;
  const int quad = lane >> 4, l16 = lane & 15;
  #pragma unroll
  for (int c2 = 0; c2 < 4; ++c2) {
    int ch = wave * 4 + c2;
    int row = ch * 8 + (lane >> 3);
    int col = (lane & 7) * 8;
    gl2lds16(Qb + ((size_t)(n0 + row) * BSZ + b) * KSTR + h * 64 + col, (void*)(qs + ch * 512));
  }
  #pragma unroll
  for (int c2 = 0; c2 < 2; ++c2) {
    int ch = wave * 2 + c2;
    int e = ch * 8 + (lane >> 3);
    int col = (lane & 7) * 8;
    gl2lds16(kvT + (size_t)bh * 4096 + e * 64 + col, (void*)(kvs + ch * 512));
  }
  if (tid < 64) kms[tid] = km[b * CD + h * 64 + tid];
  __syncthreads();
  if (tid < 128) {
    float s = 0.f;
    for (int d2 = 0; d2 < 64; ++d2) s += b2f(qs[tid * 64 + d2]) * kms[d2];
    zs[tid] = 1.f / (s + EPSF);
  }
  __syncthreads();
  f32x4 acc[2][4] = {};
  #pragma unroll
  for (int kh = 0; kh < 2; ++kh) {
    bf16x8 a0 = *(const bf16x8*)(qs + (wave * 32 + l16) * 64 + kh * 32 + quad * 8);
    bf16x8 a1 = *(const bf16x8*)(qs + (wave * 32 + 16 + l16) * 64 + kh * 32 + quad * 8);
    bf16x8 bt[4];
    #pragma unroll
    for (int tn = 0; tn < 4; ++tn)
      bt[tn] = *(const bf16x8*)(kvs + (tn * 16 + l16) * 64 + kh * 32 + quad * 8);
    #pragma unroll
    for (int tn = 0; tn < 4; ++tn) {
      acc[0][tn] = __builtin_amdgcn_mfma_f32_16x16x32_bf16(a0, bt[tn], acc[0][tn], 0, 0, 0);
      acc[1][tn] = __builtin_amdgcn_mfma_f32_16x16x32_bf16(a1, bt[tn], acc[1][tn], 0, 0, 0);
    }
  }
  #pragma unroll
  for (int tm = 0; tm < 2; ++tm)
    #pragma unroll
    for (int tn = 0; tn < 4; ++tn)
      #pragma unroll
      for (int r = 0; r < 4; ++r) {
        int rl = wave * 32 + tm * 16 + quad * 4 + r;
        int n = n0 + rl;
        int m = n & (NM_ - 1);
        int c = h * 64 + tn * 16 + l16;
        float val = acc[tm][tn][r] * zs[rl] + b2f(dwcb[((size_t)m * BSZ + b) * CD + c]);
        tmpb[((size_t)n * BSZ + b) * CD + c] = bf16r(val);
      }
}

// =============================== launcher ===============================
extern "C" void kernel_launch(void* const* d_in, const int* in_sizes, int n_in,
                              void* d_out, int out_size, void* d_ws, size_t ws_size,
                              hipStream_t stream) {
  const float* x      = (const float*)d_in[0];
  const float* memory = (const float*)d_in[1];
  const float* w_q    = (const float*)d_in[2];
  const float* w_k    = (const float*)d_in[3];
  const float* w_v    = (const float*)d_in[4];
  const float* w_proj = (const float*)d_in[5];
  const float* b_proj = (const float*)d_in[6];
  const float* dwc_w  = (const float*)d_in[7];
  const float* dwc_b  = (const float*)d_in[8];
  const float* scale  = (const float*)d_in[9];
  float* out = (float*)d_out;

  const int Mq = NX_ * BSZ;   // 32768
  const int Mm = NM_ * BSZ;   // 8192

  char* ws = (char*)d_ws;
  size_t off = 0;
  auto alloc = [&](size_t bytes) -> void* {
    void* p = ws + off;
    off += (bytes + 255) & ~(size_t)255;
    return p;
  };
  float* q    = (float*)alloc((size_t)Mq * CD * 4);   // fp32, later bf16 in-place (stride KSTR)
  float* kbuf = (float*)alloc((size_t)Mm * CD * 4);   // fp32, later bf16 in-place
  float* kvp  = (float*)alloc((size_t)KVCH * 24 * 4096 * 4);   // 12.6 MB partials
  float* kmp  = (float*)alloc((size_t)KVCH * 24 * 64 * 4);
  float* km   = (float*)alloc((size_t)BSZ * CD * 4);
  float* sp   = (float*)alloc(CD * 4);
  unsigned short* tmpb = (unsigned short*)alloc((size_t)Mq * CD * 2);
  unsigned short* vb   = (unsigned short*)alloc((size_t)Mm * CD * 2);  // bf16 v
  unsigned short* dwcb = (unsigned short*)alloc((size_t)Mm * CD * 2);
  unsigned short* kvT  = (unsigned short*)alloc((size_t)BSZ * NHEAD * DH * DH * 2);
  unsigned short* wqb  = (unsigned short*)alloc((size_t)CD * CD * 2);
  unsigned short* wkb  = (unsigned short*)alloc((size_t)CD * CD * 2);
  unsigned short* wvb  = (unsigned short*)alloc((size_t)CD * CD * 2);
  unsigned short* wpb  = (unsigned short*)alloc((size_t)CD * CD * 2);

  prep_k<<<2307, 256, 0, stream>>>(w_q, w_k, w_v, w_proj, scale, wqb, wkb, wvb, wpb, sp);

  const int gq = (Mq / 128) * (CD / 128);   // 1536, div by 8 -> XCD swizzle active
  const int gm = (Mm / 128) * (CD / 128);   // 384,  div by 8
  gemm128<1, 0><<<gq, 256, 0, stream>>>(x,      wqb, q,    nullptr, Mq, CD, CD);
  gemm128<1, 0><<<gm, 256, 0, stream>>>(memory, wkb, kbuf, nullptr, Mm, CD, CD);
  gemm128<1, 1><<<gm, 256, 0, stream>>>(memory, wvb, vb,   nullptr, Mm, CD, CD);

  process_rows<<<Mq, 256, 0, stream>>>(q, sp);     // q -> bf16 in-place
  process_rows<<<Mm, 256, 0, stream>>>(kbuf, sp);  // k -> bf16 in-place

  const unsigned short* qb = (const unsigned short*)q;
  const unsigned short* kb = (const unsigned short*)kbuf;

  kv_part_k<<<dim3(24, KVCH), 256, 0, stream>>>(kb, vb, kvp, kmp);
  kv_reduce_k<<<30, 256, 0, stream>>>(kvp, kmp, kvT, km);

  dwconv_k<<<dim3(BSZ * NHEAD, 16), 256, 0, stream>>>(vb, dwc_w, dwc_b, dwcb);

  attn_mfma<<<dim3(BSZ * NHEAD, NX_ / 128), 256, 0, stream>>>(qb, kvT, km, dwcb, tmpb);

  gemm128<0, 0><<<gq, 256, 0, stream>>>(tmpb, wpb, out, b_proj, Mq, CD, CD);
}

// Round 3
// 515.710 us; speedup vs baseline: 1.0245x; 1.0240x over previous
//
#include <hip/hip_runtime.h>

#define CD 768
#define NHEAD 12
#define DH 64
#define BSZ 2
#define NM_ 4096
#define NX_ 16384
#define EPSF 1e-6f
#define KSTR 1536   // ushort stride of in-place bf16 rows inside an fp32 buffer
#define KVCH 32     // split-K chunks for kv partials

using bf16x8 = __attribute__((ext_vector_type(8))) short;
using f32x4  = __attribute__((ext_vector_type(4))) float;

__device__ inline unsigned short bf16r(float f) {
  union { float f; unsigned u; } un; un.f = f;
  unsigned u = un.u;
  u += 0x7fffu + ((u >> 16) & 1u);
  return (unsigned short)(u >> 16);
}
__device__ inline float b2f(unsigned short u) {
  union { unsigned u; float f; } x; x.u = ((unsigned)u) << 16; return x.f;
}
__device__ inline float asf(unsigned u) {
  union { unsigned u; float f; } x; x.u = u; return x.f;
}
// async global->LDS, 16B per lane; LDS dest = wave-uniform base + lane*16
__device__ inline void gl2lds16(const void* g, void* l) {
  __builtin_amdgcn_global_load_lds(
      (const __attribute__((address_space(1))) void*)g,
      (__attribute__((address_space(3))) void*)l, 16, 0, 0);
}

// ---- prep: 4 weight matrices fp32->bf16 + softplus(scale), ONE dispatch ----
__global__ __launch_bounds__(256) void prep_k(const float* __restrict__ w0, const float* __restrict__ w1,
                                              const float* __restrict__ w2, const float* __restrict__ w3,
                                              const float* __restrict__ scale,
                                              unsigned short* __restrict__ o0, unsigned short* __restrict__ o1,
                                              unsigned short* __restrict__ o2, unsigned short* __restrict__ o3,
                                              float* __restrict__ sp) {
  int bx = blockIdx.x;
  if (bx < 2304) {                    // 4 matrices x 576 blocks x 256 float4
    int m = bx / 576;
    int i = (bx % 576) * 256 + threadIdx.x;
    const float* w = m == 0 ? w0 : m == 1 ? w1 : m == 2 ? w2 : w3;
    unsigned short* o = m == 0 ? o0 : m == 1 ? o1 : m == 2 ? o2 : o3;
    float4 v = ((const float4*)w)[i];
    ushort4 u; u.x = bf16r(v.x); u.y = bf16r(v.y); u.z = bf16r(v.z); u.w = bf16r(v.w);
    ((ushort4*)o)[i] = u;
  } else {
    int i = (bx - 2304) * 256 + threadIdx.x;
    if (i < CD) sp[i] = log1pf(expf(scale[i]));
  }
}

// ---- fp32 -> bf16 bulk convert: thread i converts 8 elements (32B in, 16B out)
__global__ __launch_bounds__(256) void cvt_k(const float* __restrict__ s,
                                             unsigned short* __restrict__ d, int n8) {
  int i = blockIdx.x * 256 + threadIdx.x;
  if (i >= n8) return;
  const float4* sp = (const float4*)s;
  float4 f0 = sp[(size_t)i * 2], f1 = sp[(size_t)i * 2 + 1];
  unsigned short u[8];
  u[0] = bf16r(f0.x); u[1] = bf16r(f0.y); u[2] = bf16r(f0.z); u[3] = bf16r(f0.w);
  u[4] = bf16r(f1.x); u[5] = bf16r(f1.y); u[6] = bf16r(f1.z); u[7] = bf16r(f1.w);
  *(int4*)(d + (size_t)i * 8) = *(int4*)u;
}

// ------- 128x128-tile GEMM (bf16 A): C[M,N] = A[M,K] @ B[N,K]^T (+bias) -----
// Proven round-0 structure (no XCD swizzle). Used for the small M=8192 GEMMs
// where 128-tiles give 4x the CU coverage of 256-tiles.
template<int OUTBF>
__global__ __launch_bounds__(256) void gemm128(const unsigned short* __restrict__ A,
                                               const unsigned short* __restrict__ B,
                                               void* __restrict__ Cv,
                                               const float* __restrict__ bias,
                                               int M, int N, int K) {
  __shared__ __align__(16) unsigned short As[128 * 32];
  __shared__ __align__(16) unsigned short Bs[128 * 32];
  const int m0 = blockIdx.x * 128, n0 = blockIdx.y * 128;
  const int tid = threadIdx.x, wave = tid >> 6, lane = tid & 63;
  const int quad = lane >> 4, l16 = lane & 15;
  const int wm = (wave >> 1) * 64, wn = (wave & 1) * 64;
  const int srow = lane >> 2, scol = (lane & 3) * 8;  // gl2lds: 16 rows/chunk, 4 lanes/row
  f32x4 acc[4][4] = {};
  for (int k0 = 0; k0 < K; k0 += 32) {
    __syncthreads();
    #pragma unroll
    for (int c2 = 0; c2 < 2; ++c2) {
      int ch = wave * 2 + c2;
      gl2lds16(A + (size_t)(m0 + ch * 16 + srow) * K + k0 + scol, (void*)(As + ch * 512));
      gl2lds16(B + (size_t)(n0 + ch * 16 + srow) * K + k0 + scol, (void*)(Bs + ch * 512));
    }
    __syncthreads();
    bf16x8 a[4], bb[4];
    #pragma unroll
    for (int t = 0; t < 4; ++t) {
      a[t]  = *(const bf16x8*)(As + (wm + t * 16 + l16) * 32 + quad * 8);
      bb[t] = *(const bf16x8*)(Bs + (wn + t * 16 + l16) * 32 + quad * 8);
    }
    #pragma unroll
    for (int tm = 0; tm < 4; ++tm)
      #pragma unroll
      for (int tn = 0; tn < 4; ++tn)
        acc[tm][tn] = __builtin_amdgcn_mfma_f32_16x16x32_bf16(a[tm], bb[tn], acc[tm][tn], 0, 0, 0);
  }
  // D layout: col = lane&15, row = quad*4 + r  [m89/m91 verified]
  #pragma unroll
  for (int tm = 0; tm < 4; ++tm)
    #pragma unroll
    for (int tn = 0; tn < 4; ++tn) {
      const int col = n0 + wn + tn * 16 + l16;
      const float bv = bias ? bias[col] : 0.f;
      #pragma unroll
      for (int r = 0; r < 4; ++r) {
        const int row = m0 + wm + tm * 16 + quad * 4 + r;
        float v = acc[tm][tn][r] + bv;
        if (OUTBF) ((unsigned short*)Cv)[(size_t)row * N + col] = bf16r(v);
        else       ((float*)Cv)[(size_t)row * N + col] = v;
      }
    }
}

// ======== 256x256-tile deep-pipelined GEMM: C[M,N] = A[M,K] @ B[N,K]^T ======
// 512 threads = 8 waves (2M x 4N), per-wave 128x64 output, acc[8][4] f32x4.
// K consumed in 24 slices of BK=32; 4-deep LDS ring (A,B slices, 128 KiB total).
// Counted vmcnt(8) keeps 3 slices (12 gl2lds) in flight across barriers (T3+T4).
// LDS XOR-swizzle: chunk c' = c ^ ((row>>1)&3), applied on the pre-swizzled
// global source (gl2lds writes linearly, rule #21); ds_read uses the same XOR.
template<int OUTBF>
__global__ __launch_bounds__(512, 2) void gemm256(const unsigned short* __restrict__ A,
                                                  const unsigned short* __restrict__ B,
                                                  void* __restrict__ Cv,
                                                  const float* __restrict__ bias,
                                                  int M, int N, int K) {
  __shared__ __align__(16) unsigned short As[4][256 * 32];
  __shared__ __align__(16) unsigned short Bs[4][256 * 32];
  const int m0 = blockIdx.x * 256, n0 = blockIdx.y * 256;
  const int tid = threadIdx.x, w = tid >> 6, lane = tid & 63;
  const int quad = lane >> 4, l16 = lane & 15;
  const int wm = (w >> 2) * 128, wn = (w & 3) * 64;
  const int NS = K >> 5;
  // staging map: linear LDS off = i*8192 + w*1024 + lane*16 -> (row, chunk)
  const int srow = 16 * w + (lane >> 2);          // issue 0 row; issue 1 = +128
  const int c0 = lane & 3;
  const int scol = (c0 ^ ((srow >> 1) & 3)) * 8;  // pre-swizzled global chunk
  const size_t arow = (size_t)(m0 + srow) * K;
  const size_t brow = (size_t)(n0 + srow) * K;
  // frag-read swizzle: row = base16 + l16 -> chunk = quad ^ ((l16>>1)&3)
  const int fq = (quad ^ ((l16 >> 1) & 3)) * 8;

  auto stage2 = [&](const unsigned short* __restrict__ G, size_t rb, int kcol,
                    unsigned short* lds) {
    gl2lds16(G + rb + kcol, (void*)lds);
    gl2lds16(G + rb + (size_t)128 * K + kcol, (void*)(lds + 4096));
    asm volatile("" ::: "memory");   // pin issue order (vmcnt retirement counting)
  };
#define SA_(slot) (&As[slot][0] + w * 512)
#define SB_(slot) (&Bs[slot][0] + w * 512)

  f32x4 acc[8][4] = {};
  // prologue: stage slices 0,1,2 into ring slots 0,1,2 (12 loads/wave in flight)
  stage2(A, arow, 0 * 32 + scol, SA_(0));
  stage2(B, brow, 0 * 32 + scol, SB_(0));
  stage2(A, arow, 1 * 32 + scol, SA_(1));
  stage2(B, brow, 1 * 32 + scol, SB_(1));
  stage2(A, arow, 2 * 32 + scol, SA_(2));
  stage2(B, brow, 2 * 32 + scol, SB_(2));

  for (int s = 0; s < NS; ++s) {
    // retire this slice's 4 loads; keep up to 2 future slices (8 loads) in flight
    if (s < NS - 2)       asm volatile("s_waitcnt vmcnt(8)" ::: "memory");
    else if (s == NS - 2) asm volatile("s_waitcnt vmcnt(4)" ::: "memory");
    else                  asm volatile("s_waitcnt vmcnt(0)" ::: "memory");
    __builtin_amdgcn_s_barrier();
    asm volatile("" ::: "memory");
    const int slot = s & 3, nslot = (s + 3) & 3;
    const unsigned short* sa = &As[slot][0];
    const unsigned short* sb = &Bs[slot][0];
    const bool st = (s + 3) < NS;
    // ---- phase A: m-frags 0..3 x n-frags 0..3 ----
    bf16x8 av[4], bv[4];
    #pragma unroll
    for (int f = 0; f < 4; ++f) {
      av[f] = *(const bf16x8*)(sa + (wm + f * 16 + l16) * 32 + fq);
      bv[f] = *(const bf16x8*)(sb + (wn + f * 16 + l16) * 32 + fq);
    }
    if (st) stage2(A, arow, (s + 3) * 32 + scol, SA_(nslot));
    __builtin_amdgcn_s_setprio(1);
    #pragma unroll
    for (int mf = 0; mf < 4; ++mf)
      #pragma unroll
      for (int nf = 0; nf < 4; ++nf)
        acc[mf][nf] = __builtin_amdgcn_mfma_f32_16x16x32_bf16(av[mf], bv[nf], acc[mf][nf], 0, 0, 0);
    __builtin_amdgcn_s_setprio(0);
    // ---- phase B: m-frags 4..7 x n-frags 0..3 (B frags reused) ----
    bf16x8 aw[4];
    #pragma unroll
    for (int f = 0; f < 4; ++f)
      aw[f] = *(const bf16x8*)(sa + (wm + 64 + f * 16 + l16) * 32 + fq);
    if (st) stage2(B, brow, (s + 3) * 32 + scol, SB_(nslot));
    __builtin_amdgcn_s_setprio(1);
    #pragma unroll
    for (int mf = 0; mf < 4; ++mf)
      #pragma unroll
      for (int nf = 0; nf < 4; ++nf)
        acc[4 + mf][nf] = __builtin_amdgcn_mfma_f32_16x16x32_bf16(aw[mf], bv[nf], acc[4 + mf][nf], 0, 0, 0);
    __builtin_amdgcn_s_setprio(0);
  }
#undef SA_
#undef SB_
  // D layout: col = lane&15, row = quad*4 + r  [m89/m91 verified]
  #pragma unroll
  for (int mf = 0; mf < 8; ++mf)
    #pragma unroll
    for (int nf = 0; nf < 4; ++nf) {
      const int col = n0 + wn + nf * 16 + l16;
      const float bvl = bias ? bias[col] : 0.f;
      #pragma unroll
      for (int r = 0; r < 4; ++r) {
        const int row = m0 + wm + mf * 16 + quad * 4 + r;
        float v = acc[mf][nf][r] + bvl;
        if (OUTBF) ((unsigned short*)Cv)[(size_t)row * N + col] = bf16r(v);
        else       ((float*)Cv)[(size_t)row * N + col] = v;
      }
    }
}

// ------- _process: read fp32 row, write bf16 row IN-PLACE (stride KSTR) -------
__global__ __launch_bounds__(256) void process_rows(float* __restrict__ X,
                                                    const float* __restrict__ sp) {
  const int row = blockIdx.x;
  const int tid = threadIdx.x;
  float* xr = X + (size_t)row * CD;
  float tv[3];
  float n2 = 0.f, m2 = 0.f;
  #pragma unroll
  for (int i = 0; i < 3; ++i) {
    int c = tid + i * 256;
    float t = fmaxf(xr[c], 0.f) + EPSF;
    t = t / sp[c];
    tv[i] = t;
    float t2 = t * t;
    n2 += t2;
    float p = t2 * t;
    m2 += p * p;
  }
  #pragma unroll
  for (int off = 32; off; off >>= 1) {
    n2 += __shfl_down(n2, off, 64);
    m2 += __shfl_down(m2, off, 64);
  }
  __shared__ float rn[4], rm[4];
  if ((tid & 63) == 0) { rn[tid >> 6] = n2; rm[tid >> 6] = m2; }
  __syncthreads();   // also orders: all global reads done before bf16 overwrite
  float N2 = rn[0] + rn[1] + rn[2] + rn[3];
  float M2 = rm[0] + rm[1] + rm[2] + rm[3];
  float factor = sqrtf(N2 / M2);   // = ||t|| / ||t^3||
  unsigned short* xo = (unsigned short*)xr;
  #pragma unroll
  for (int i = 0; i < 3; ++i) {
    int c = tid + i * 256;
    float t = tv[i];
    xo[c] = bf16r(t * t * t * factor);
  }
}

// ---- kv partials: kvp[ch][bh][d][e] = sum_{n in chunk} k[n,d]*v[n,e] --------
__global__ __launch_bounds__(256) void kv_part_k(const unsigned short* __restrict__ Kp,
                                                 const unsigned short* __restrict__ Vp,
                                                 float* __restrict__ kvp,
                                                 float* __restrict__ kmp) {
  const int bh = blockIdx.x, chunk = blockIdx.y;
  const int b = bh / NHEAD, h = bh % NHEAD;
  const int n0 = chunk * 128;
  __shared__ __align__(16) unsigned short ks[128 * 72];
  __shared__ __align__(16) unsigned short vs[128 * 72];
  const int tid = threadIdx.x;
  #pragma unroll
  for (int it = 0; it < 4; ++it) {
    int g = it * 256 + tid;            // 1024 groups of 8 elements per tile
    int row = g >> 3, c8 = (g & 7) * 8;
    int4 ka = *(const int4*)(Kp + ((size_t)(n0 + row) * BSZ + b) * KSTR + h * 64 + c8);
    int4 va = *(const int4*)(Vp + ((size_t)(n0 + row) * BSZ + b) * CD + h * 64 + c8);
    *(int4*)(ks + row * 72 + c8) = ka;
    *(int4*)(vs + row * 72 + c8) = va;
  }
  __syncthreads();
  const int d0 = (tid >> 4) * 4, e0 = (tid & 15) * 4;
  float acc[4][4] = {};
  #pragma unroll 4
  for (int n = 0; n < 128; ++n) {
    ushort4 kd = *(const ushort4*)(ks + n * 72 + d0);
    ushort4 ve = *(const ushort4*)(vs + n * 72 + e0);
    float kf[4] = {b2f(kd.x), b2f(kd.y), b2f(kd.z), b2f(kd.w)};
    float vf[4] = {b2f(ve.x), b2f(ve.y), b2f(ve.z), b2f(ve.w)};
    #pragma unroll
    for (int i = 0; i < 4; ++i)
      #pragma unroll
      for (int j = 0; j < 4; ++j) acc[i][j] += kf[i] * vf[j];
  }
  float* outp = kvp + ((size_t)chunk * 24 + bh) * 4096;
  #pragma unroll
  for (int i = 0; i < 4; ++i) {
    float4 o; o.x = acc[i][0]; o.y = acc[i][1]; o.z = acc[i][2]; o.w = acc[i][3];
    *(float4*)(outp + (d0 + i) * 64 + e0) = o;
  }
  if (tid < 64) {
    float s = 0.f;
    for (int n = 0; n < 128; ++n) s += b2f(ks[n * 72 + tid]);
    kmp[((size_t)chunk * 24 + bh) * 64 + tid] = s;
  }
}

// ---- reduce partials -> kvT[bh][e][d] bf16 (+1/Nm) and km[b][c] fp32 --------
__global__ __launch_bounds__(256) void kv_reduce_k(const float* __restrict__ kvp,
                                                   const float* __restrict__ kmp,
                                                   unsigned short* __restrict__ kvT,
                                                   float* __restrict__ km) {
  const int tid = threadIdx.x;
  const int bx = blockIdx.x;
  if (bx < 24) {
    __shared__ float t[64 * 65];
    float acc[16] = {};
    const float* base = kvp + (size_t)bx * 4096 + tid * 16;
    for (int c = 0; c < KVCH; ++c) {
      const float* p = base + (size_t)c * 24 * 4096;
      #pragma unroll
      for (int i = 0; i < 4; ++i) {
        float4 v = *(const float4*)(p + i * 4);
        acc[i * 4 + 0] += v.x; acc[i * 4 + 1] += v.y; acc[i * 4 + 2] += v.z; acc[i * 4 + 3] += v.w;
      }
    }
    const int d = tid >> 2, e0 = (tid & 3) * 16;   // writes row d, cols e0..e0+15
    #pragma unroll
    for (int i = 0; i < 16; ++i) t[d * 65 + e0 + i] = acc[i] * (1.f / NM_);
    __syncthreads();
    const int e = tid >> 2, dd0 = (tid & 3) * 16;  // read col e, rows dd0..+15
    ushort4 o[4];
    #pragma unroll
    for (int i = 0; i < 16; ++i)
      ((unsigned short*)o)[i] = bf16r(t[(dd0 + i) * 65 + e]);
    unsigned short* dst = kvT + (size_t)bx * 4096 + e * 64 + dd0;
    *(ushort4*)(dst) = o[0]; *(ushort4*)(dst + 4) = o[1];
    *(ushort4*)(dst + 8) = o[2]; *(ushort4*)(dst + 12) = o[3];
  } else {
    int i = (bx - 24) * 256 + tid;                 // 6 blocks cover 1536 outputs
    if (i < 24 * 64) {
      int bhh = i >> 6, d = i & 63;
      float s = 0.f;
      for (int c = 0; c < KVCH; ++c) s += kmp[((size_t)c * 24 + bhh) * 64 + d];
      int b = bhh / NHEAD, h = bhh % NHEAD;
      km[b * CD + h * 64 + d] = s * (1.f / NM_);
    }
  }
}

// -------- depthwise 5x5 conv, LDS-tiled: block = (b,h) x 16-wide x-tile ------
__global__ __launch_bounds__(256) void dwconv_k(const unsigned short* __restrict__ Vp,
                                                const float* __restrict__ w,
                                                const float* __restrict__ bias,
                                                unsigned short* __restrict__ outp) {
  __shared__ __align__(16) unsigned ls32[16 * 20 * 32];  // ushort2-packed channels
  __shared__ float wsm[64 * 25];
  __shared__ float bsm[64];
  const int tid = threadIdx.x;
  const int bh = blockIdx.x, b = bh / NHEAD, h = bh % NHEAD;
  const int x0 = blockIdx.y * 16;
  for (int i = tid; i < 1600; i += 256) wsm[i] = w[i];
  if (tid < 64) bsm[tid] = bias[tid];
  const int lch = (tid & 7) * 8;
  #pragma unroll
  for (int it = 0; it < 10; ++it) {
    int p = it * 32 + (tid >> 3);
    int y = p / 20, xp = p % 20;
    int xx = x0 + xp - 2;
    int4 val = {0, 0, 0, 0};
    if (xx >= 0 && xx < 256)
      val = *(const int4*)(Vp + ((size_t)((y << 8) + xx) * BSZ + b) * CD + h * 64 + lch);
    *(int4*)((unsigned short*)ls32 + p * 64 + lch) = val;
  }
  __syncthreads();
  const int cp = tid & 31;        // channel pair: ch = {2cp, 2cp+1}
  const int xs = tid >> 5;        // 0..7 -> x outputs {2xs, 2xs+1}
  float wr0[25], wr1[25];
  #pragma unroll
  for (int t = 0; t < 25; ++t) { wr0[t] = wsm[(cp * 2) * 25 + t]; wr1[t] = wsm[(cp * 2 + 1) * 25 + t]; }
  const float b0 = bsm[cp * 2], b1 = bsm[cp * 2 + 1];
  for (int y = 0; y < 16; ++y) {
    float a00 = b0, a01 = b1, a10 = b0, a11 = b1;
    #pragma unroll
    for (int dy = 0; dy < 5; ++dy) {
      int yy = y + dy - 2;
      if (yy < 0 || yy >= 16) continue;
      #pragma unroll
      for (int dx = 0; dx < 5; ++dx) {
        int base = (yy * 20 + xs * 2 + dx) * 32 + cp;
        unsigned u0 = ls32[base], u1 = ls32[base + 32];
        float w0 = wr0[dy * 5 + dx], w1 = wr1[dy * 5 + dx];
        a00 += w0 * asf(u0 << 16);  a01 += w1 * asf(u0 & 0xffff0000u);
        a10 += w0 * asf(u1 << 16);  a11 += w1 * asf(u1 & 0xffff0000u);
      }
    }
    const int x = x0 + xs * 2;
    size_t o = ((size_t)((y << 8) + x) * BSZ + b) * CD + h * 64 + cp * 2;
    ushort2 s0; s0.x = bf16r(a00); s0.y = bf16r(a01);
    ushort2 s1; s1.x = bf16r(a10); s1.y = bf16r(a11);
    *(ushort2*)(outp + o) = s0;
    *(ushort2*)(outp + o + (size_t)BSZ * CD) = s1;
  }
}

// ------ attn: tmp = bf16( z * (q @ kv) + dwc ), MFMA per head, K=64 ---------
__global__ __launch_bounds__(256) void attn_mfma(const unsigned short* __restrict__ Qb,
                                                 const unsigned short* __restrict__ kvT,
                                                 const float* __restrict__ km,
                                                 const unsigned short* __restrict__ dwcb,
                                                 unsigned short* __restrict__ tmpb) {
  __shared__ __align__(16) unsigned short qs[128 * 64];
  __shared__ __align__(16) unsigned short kvs[64 * 64];
  __shared__ float kms[64];
  __shared__ float zs[128];
  const int bh = blockIdx.x, b = bh / NHEAD, h = bh % NHEAD;
  const int n0 = blockIdx.y * 128;
  const int tid = threadIdx.x, wave = tid >> 6, lane = tid & 63;
  const int quad = lane >> 4, l16 = lane & 15;
  #pragma unroll
  for (int c2 = 0; c2 < 4; ++c2) {
    int ch = wave * 4 + c2;
    int row = ch * 8 + (lane >> 3);
    int col = (lane & 7) * 8;
    gl2lds16(Qb + ((size_t)(n0 + row) * BSZ + b) * KSTR + h * 64 + col, (void*)(qs + ch * 512));
  }
  #pragma unroll
  for (int c2 = 0; c2 < 2; ++c2) {
    int ch = wave * 2 + c2;
    int e = ch * 8 + (lane >> 3);
    int col = (lane & 7) * 8;
    gl2lds16(kvT + (size_t)bh * 4096 + e * 64 + col, (void*)(kvs + ch * 512));
  }
  if (tid < 64) kms[tid] = km[b * CD + h * 64 + tid];
  __syncthreads();
  if (tid < 128) {
    float s = 0.f;
    for (int d2 = 0; d2 < 64; ++d2) s += b2f(qs[tid * 64 + d2]) * kms[d2];
    zs[tid] = 1.f / (s + EPSF);
  }
  __syncthreads();
  f32x4 acc[2][4] = {};
  #pragma unroll
  for (int kh = 0; kh < 2; ++kh) {
    bf16x8 a0 = *(const bf16x8*)(qs + (wave * 32 + l16) * 64 + kh * 32 + quad * 8);
    bf16x8 a1 = *(const bf16x8*)(qs + (wave * 32 + 16 + l16) * 64 + kh * 32 + quad * 8);
    bf16x8 bt[4];
    #pragma unroll
    for (int tn = 0; tn < 4; ++tn)
      bt[tn] = *(const bf16x8*)(kvs + (tn * 16 + l16) * 64 + kh * 32 + quad * 8);
    #pragma unroll
    for (int tn = 0; tn < 4; ++tn) {
      acc[0][tn] = __builtin_amdgcn_mfma_f32_16x16x32_bf16(a0, bt[tn], acc[0][tn], 0, 0, 0);
      acc[1][tn] = __builtin_amdgcn_mfma_f32_16x16x32_bf16(a1, bt[tn], acc[1][tn], 0, 0, 0);
    }
  }
  #pragma unroll
  for (int tm = 0; tm < 2; ++tm)
    #pragma unroll
    for (int tn = 0; tn < 4; ++tn)
      #pragma unroll
      for (int r = 0; r < 4; ++r) {
        int rl = wave * 32 + tm * 16 + quad * 4 + r;
        int n = n0 + rl;
        int m = n & (NM_ - 1);
        int c = h * 64 + tn * 16 + l16;
        float val = acc[tm][tn][r] * zs[rl] + b2f(dwcb[((size_t)m * BSZ + b) * CD + c]);
        tmpb[((size_t)n * BSZ + b) * CD + c] = bf16r(val);
      }
}

// =============================== launcher ===============================
extern "C" void kernel_launch(void* const* d_in, const int* in_sizes, int n_in,
                              void* d_out, int out_size, void* d_ws, size_t ws_size,
                              hipStream_t stream) {
  const float* x      = (const float*)d_in[0];
  const float* memory = (const float*)d_in[1];
  const float* w_q    = (const float*)d_in[2];
  const float* w_k    = (const float*)d_in[3];
  const float* w_v    = (const float*)d_in[4];
  const float* w_proj = (const float*)d_in[5];
  const float* b_proj = (const float*)d_in[6];
  const float* dwc_w  = (const float*)d_in[7];
  const float* dwc_b  = (const float*)d_in[8];
  const float* scale  = (const float*)d_in[9];
  float* out = (float*)d_out;

  const int Mq = NX_ * BSZ;   // 32768
  const int Mm = NM_ * BSZ;   // 8192

  char* ws = (char*)d_ws;
  size_t off = 0;
  auto alloc = [&](size_t bytes) -> void* {
    void* p = ws + off;
    off += (bytes + 255) & ~(size_t)255;
    return p;
  };
  float* q    = (float*)alloc((size_t)Mq * CD * 4);   // fp32, later bf16 in-place (stride KSTR)
  float* kbuf = (float*)alloc((size_t)Mm * CD * 4);   // fp32, later bf16 in-place
  float* kvp  = (float*)alloc((size_t)KVCH * 24 * 4096 * 4);   // 12.6 MB partials
  float* kmp  = (float*)alloc((size_t)KVCH * 24 * 64 * 4);
  float* km   = (float*)alloc((size_t)BSZ * CD * 4);
  float* sp   = (float*)alloc(CD * 4);
  unsigned short* tmpb = (unsigned short*)alloc((size_t)Mq * CD * 2);
  unsigned short* vb   = (unsigned short*)alloc((size_t)Mm * CD * 2);  // bf16 v
  unsigned short* dwcb = (unsigned short*)alloc((size_t)Mm * CD * 2);
  unsigned short* kvT  = (unsigned short*)alloc((size_t)BSZ * NHEAD * DH * DH * 2);
  unsigned short* wqb  = (unsigned short*)alloc((size_t)CD * CD * 2);
  unsigned short* wkb  = (unsigned short*)alloc((size_t)CD * CD * 2);
  unsigned short* wvb  = (unsigned short*)alloc((size_t)CD * CD * 2);
  unsigned short* wpb  = (unsigned short*)alloc((size_t)CD * CD * 2);

  // buffer reuse (lifetimes checked): xb lives in tmpb until attn_mfma writes it;
  // memb lives in dwcb until dwconv_k writes it (k/v gemms read memb before that).
  unsigned short* xb   = tmpb;
  unsigned short* memb = dwcb;

  prep_k<<<2307, 256, 0, stream>>>(w_q, w_k, w_v, w_proj, scale, wqb, wkb, wvb, wpb, sp);

  cvt_k<<<(Mq * CD / 8 + 255) / 256, 256, 0, stream>>>(x, xb, Mq * CD / 8);
  cvt_k<<<(Mm * CD / 8 + 255) / 256, 256, 0, stream>>>(memory, memb, Mm * CD / 8);

  gemm256<0><<<dim3(Mq / 256, CD / 256), 512, 0, stream>>>(xb,   wqb, q,    nullptr, Mq, CD, CD);
  gemm128<0><<<dim3(Mm / 128, CD / 128), 256, 0, stream>>>(memb, wkb, kbuf, nullptr, Mm, CD, CD);
  gemm128<1><<<dim3(Mm / 128, CD / 128), 256, 0, stream>>>(memb, wvb, vb,   nullptr, Mm, CD, CD);

  process_rows<<<Mq, 256, 0, stream>>>(q, sp);     // q -> bf16 in-place
  process_rows<<<Mm, 256, 0, stream>>>(kbuf, sp);  // k -> bf16 in-place

  const unsigned short* qb = (const unsigned short*)q;
  const unsigned short* kb = (const unsigned short*)kbuf;

  kv_part_k<<<dim3(24, KVCH), 256, 0, stream>>>(kb, vb, kvp, kmp);
  kv_reduce_k<<<30, 256, 0, stream>>>(kvp, kmp, kvT, km);

  dwconv_k<<<dim3(BSZ * NHEAD, 16), 256, 0, stream>>>(vb, dwc_w, dwc_b, dwcb);

  attn_mfma<<<dim3(BSZ * NHEAD, NX_ / 128), 256, 0, stream>>>(qb, kvT, km, dwcb, tmpb);

  gemm256<0><<<dim3(Mq / 256, CD / 256), 512, 0, stream>>>(tmpb, wpb, out, b_proj, Mq, CD, CD);
}

// Round 4
// 514.446 us; speedup vs baseline: 1.0270x; 1.0025x over previous
//
#include <hip/hip_runtime.h>

#define CD 768
#define NHEAD 12
#define DH 64
#define BSZ 2
#define NM_ 4096
#define NX_ 16384
#define EPSF 1e-6f
#define KSTR 1536   // ushort stride of in-place bf16 rows inside an fp32 buffer
#define KVCH 32     // split-K chunks for kv partials

using bf16x8 = __attribute__((ext_vector_type(8))) short;
using f32x4  = __attribute__((ext_vector_type(4))) float;

__device__ inline unsigned short bf16r(float f) {
  union { float f; unsigned u; } un; un.f = f;
  unsigned u = un.u;
  u += 0x7fffu + ((u >> 16) & 1u);
  return (unsigned short)(u >> 16);
}
__device__ inline float b2f(unsigned short u) {
  union { unsigned u; float f; } x; x.u = ((unsigned)u) << 16; return x.f;
}
__device__ inline float asf(unsigned u) {
  union { unsigned u; float f; } x; x.u = u; return x.f;
}
// async global->LDS, 16B per lane; LDS dest = wave-uniform base + lane*16
__device__ inline void gl2lds16(const void* g, void* l) {
  __builtin_amdgcn_global_load_lds(
      (const __attribute__((address_space(1))) void*)g,
      (__attribute__((address_space(3))) void*)l, 16, 0, 0);
}

// ---- prep: 4 weight matrices fp32->bf16 + softplus(scale), ONE dispatch ----
__global__ __launch_bounds__(256) void prep_k(const float* __restrict__ w0, const float* __restrict__ w1,
                                              const float* __restrict__ w2, const float* __restrict__ w3,
                                              const float* __restrict__ scale,
                                              unsigned short* __restrict__ o0, unsigned short* __restrict__ o1,
                                              unsigned short* __restrict__ o2, unsigned short* __restrict__ o3,
                                              float* __restrict__ sp) {
  int bx = blockIdx.x;
  if (bx < 2304) {                    // 4 matrices x 576 blocks x 256 float4
    int m = bx / 576;
    int i = (bx % 576) * 256 + threadIdx.x;
    const float* w = m == 0 ? w0 : m == 1 ? w1 : m == 2 ? w2 : w3;
    unsigned short* o = m == 0 ? o0 : m == 1 ? o1 : m == 2 ? o2 : o3;
    float4 v = ((const float4*)w)[i];
    ushort4 u; u.x = bf16r(v.x); u.y = bf16r(v.y); u.z = bf16r(v.z); u.w = bf16r(v.w);
    ((ushort4*)o)[i] = u;
  } else {
    int i = (bx - 2304) * 256 + threadIdx.x;
    if (i < CD) sp[i] = log1pf(expf(scale[i]));
  }
}

// ---- fp32 -> bf16 bulk convert: thread i converts 8 elements (32B in, 16B out)
__global__ __launch_bounds__(256) void cvt_k(const float* __restrict__ s,
                                             unsigned short* __restrict__ d, int n8) {
  int i = blockIdx.x * 256 + threadIdx.x;
  if (i >= n8) return;
  const float4* sp = (const float4*)s;
  float4 f0 = sp[(size_t)i * 2], f1 = sp[(size_t)i * 2 + 1];
  unsigned short u[8];
  u[0] = bf16r(f0.x); u[1] = bf16r(f0.y); u[2] = bf16r(f0.z); u[3] = bf16r(f0.w);
  u[4] = bf16r(f1.x); u[5] = bf16r(f1.y); u[6] = bf16r(f1.z); u[7] = bf16r(f1.w);
  *(int4*)(d + (size_t)i * 8) = *(int4*)u;
}

// ------- 128x128-tile GEMM (bf16 A): C[M,N] = A[M,K] @ B[N,K]^T (+bias) -----
// Proven round-0 structure (no XCD swizzle). Used for the small M=8192 GEMMs
// where 128-tiles give 4x the CU coverage of 256-tiles.
template<int OUTBF>
__global__ __launch_bounds__(256) void gemm128(const unsigned short* __restrict__ A,
                                               const unsigned short* __restrict__ B,
                                               void* __restrict__ Cv,
                                               const float* __restrict__ bias,
                                               int M, int N, int K) {
  __shared__ __align__(16) unsigned short As[128 * 32];
  __shared__ __align__(16) unsigned short Bs[128 * 32];
  const int m0 = blockIdx.x * 128, n0 = blockIdx.y * 128;
  const int tid = threadIdx.x, wave = tid >> 6, lane = tid & 63;
  const int quad = lane >> 4, l16 = lane & 15;
  const int wm = (wave >> 1) * 64, wn = (wave & 1) * 64;
  const int srow = lane >> 2, scol = (lane & 3) * 8;  // gl2lds: 16 rows/chunk, 4 lanes/row
  f32x4 acc[4][4] = {};
  for (int k0 = 0; k0 < K; k0 += 32) {
    __syncthreads();
    #pragma unroll
    for (int c2 = 0; c2 < 2; ++c2) {
      int ch = wave * 2 + c2;
      gl2lds16(A + (size_t)(m0 + ch * 16 + srow) * K + k0 + scol, (void*)(As + ch * 512));
      gl2lds16(B + (size_t)(n0 + ch * 16 + srow) * K + k0 + scol, (void*)(Bs + ch * 512));
    }
    __syncthreads();
    bf16x8 a[4], bb[4];
    #pragma unroll
    for (int t = 0; t < 4; ++t) {
      a[t]  = *(const bf16x8*)(As + (wm + t * 16 + l16) * 32 + quad * 8);
      bb[t] = *(const bf16x8*)(Bs + (wn + t * 16 + l16) * 32 + quad * 8);
    }
    #pragma unroll
    for (int tm = 0; tm < 4; ++tm)
      #pragma unroll
      for (int tn = 0; tn < 4; ++tn)
        acc[tm][tn] = __builtin_amdgcn_mfma_f32_16x16x32_bf16(a[tm], bb[tn], acc[tm][tn], 0, 0, 0);
  }
  // D layout: col = lane&15, row = quad*4 + r  [m89/m91 verified]
  #pragma unroll
  for (int tm = 0; tm < 4; ++tm)
    #pragma unroll
    for (int tn = 0; tn < 4; ++tn) {
      const int col = n0 + wn + tn * 16 + l16;
      const float bv = bias ? bias[col] : 0.f;
      #pragma unroll
      for (int r = 0; r < 4; ++r) {
        const int row = m0 + wm + tm * 16 + quad * 4 + r;
        float v = acc[tm][tn][r] + bv;
        if (OUTBF) ((unsigned short*)Cv)[(size_t)row * N + col] = bf16r(v);
        else       ((float*)Cv)[(size_t)row * N + col] = v;
      }
    }
}

// ======== 256x256-tile deep-pipelined GEMM: C[M,N] = A[M,K] @ B[N,K]^T ======
// 512 threads = 8 waves (2M x 4N), per-wave 128x64 output, acc[8][4] f32x4.
// K consumed in slices of BK=32; 4-deep LDS ring (128 KiB). Counted vmcnt(8)
// keeps 2 future slices (8 gl2lds) in flight across barriers (T3+T4).
// m201 phase discipline: NO memory clobbers; per slice two phases of
// {ds_read frags || issue stage || setprio-MFMA x16} separated by raw barriers.
// LDS XOR-swizzle: chunk c' = c ^ ((row>>1)&3), applied on the pre-swizzled
// global source (gl2lds writes linearly, rule #21); ds_read uses the same XOR.
template<int OUTBF>
__global__ __launch_bounds__(512, 2) void gemm256(const unsigned short* __restrict__ A,
                                                  const unsigned short* __restrict__ B,
                                                  void* __restrict__ Cv,
                                                  const float* __restrict__ bias,
                                                  int M, int N, int K) {
  __shared__ __align__(16) unsigned short As[4][256 * 32];
  __shared__ __align__(16) unsigned short Bs[4][256 * 32];
  const int m0 = blockIdx.x * 256, n0 = blockIdx.y * 256;
  const int tid = threadIdx.x, w = tid >> 6, lane = tid & 63;
  const int quad = lane >> 4, l16 = lane & 15;
  const int wm = (w >> 2) * 128, wn = (w & 3) * 64;
  const int NS = K >> 5;
  // staging map: linear LDS off = i*8192 + w*1024 + lane*16 -> (row, chunk)
  const int srow = 16 * w + (lane >> 2);          // issue 0 row; issue 1 = +128
  const int c0 = lane & 3;
  const int scol = (c0 ^ ((srow >> 1) & 3)) * 8;  // pre-swizzled global chunk
  const size_t arow = (size_t)(m0 + srow) * K;
  const size_t brow = (size_t)(n0 + srow) * K;
  // frag-read swizzle: row = base16 + l16 -> chunk = quad ^ ((l16>>1)&3)
  const int fq = (quad ^ ((l16 >> 1) & 3)) * 8;

  auto stageA = [&](int s) {
    unsigned short* l = &As[s & 3][0] + w * 512;
    const size_t col = (size_t)s * 32 + scol;
    gl2lds16(A + arow + col, (void*)l);
    gl2lds16(A + arow + (size_t)128 * K + col, (void*)(l + 4096));
  };
  auto stageB = [&](int s) {
    unsigned short* l = &Bs[s & 3][0] + w * 512;
    const size_t col = (size_t)s * 32 + scol;
    gl2lds16(B + brow + col, (void*)l);
    gl2lds16(B + brow + (size_t)128 * K + col, (void*)(l + 4096));
  };

  f32x4 acc[8][4] = {};
  // prologue: stage slices 0,1,2 into ring slots 0,1,2 (12 loads/wave in flight)
  stageA(0); stageB(0);
  stageA(1); stageB(1);
  stageA(2); stageB(2);

  for (int s = 0; s < NS; ++s) {
    // retire slice-s loads; keep up to 2 future slices (8 loads) in flight
    if (s < NS - 2)       asm volatile("s_waitcnt vmcnt(8)");
    else if (s == NS - 2) asm volatile("s_waitcnt vmcnt(4)");
    else                  asm volatile("s_waitcnt vmcnt(0)");
    __builtin_amdgcn_s_barrier();   // slot s data visible; slot s-1 fully read
    const unsigned short* sa = &As[s & 3][0];
    const unsigned short* sb = &Bs[s & 3][0];
    const bool st = (s + 3) < NS;
    // ---- phase A: m-frags 0..3 x n-frags 0..3 (16 MFMA) ----
    bf16x8 av[4], bv[4];
    #pragma unroll
    for (int f = 0; f < 4; ++f) {
      av[f] = *(const bf16x8*)(sa + (wm + f * 16 + l16) * 32 + fq);
      bv[f] = *(const bf16x8*)(sb + (wn + f * 16 + l16) * 32 + fq);
    }
    if (st) stageA(s + 3);
    __builtin_amdgcn_s_setprio(1);
    #pragma unroll
    for (int mf = 0; mf < 4; ++mf)
      #pragma unroll
      for (int nf = 0; nf < 4; ++nf)
        acc[mf][nf] = __builtin_amdgcn_mfma_f32_16x16x32_bf16(av[mf], bv[nf], acc[mf][nf], 0, 0, 0);
    __builtin_amdgcn_s_setprio(0);
    __builtin_amdgcn_s_barrier();   // phase boundary (template discipline)
    // ---- phase B: m-frags 4..7 x n-frags 0..3 (B frags reused, 16 MFMA) ----
    bf16x8 aw[4];
    #pragma unroll
    for (int f = 0; f < 4; ++f)
      aw[f] = *(const bf16x8*)(sa + (wm + 64 + f * 16 + l16) * 32 + fq);
    if (st) stageB(s + 3);
    __builtin_amdgcn_s_setprio(1);
    #pragma unroll
    for (int mf = 0; mf < 4; ++mf)
      #pragma unroll
      for (int nf = 0; nf < 4; ++nf)
        acc[4 + mf][nf] = __builtin_amdgcn_mfma_f32_16x16x32_bf16(aw[mf], bv[nf], acc[4 + mf][nf], 0, 0, 0);
    __builtin_amdgcn_s_setprio(0);
  }
  // D layout: col = lane&15, row = quad*4 + r  [m89/m91 verified]
  #pragma unroll
  for (int mf = 0; mf < 8; ++mf)
    #pragma unroll
    for (int nf = 0; nf < 4; ++nf) {
      const int col = n0 + wn + nf * 16 + l16;
      const float bvl = bias ? bias[col] : 0.f;
      #pragma unroll
      for (int r = 0; r < 4; ++r) {
        const int row = m0 + wm + mf * 16 + quad * 4 + r;
        float v = acc[mf][nf][r] + bvl;
        if (OUTBF) ((unsigned short*)Cv)[(size_t)row * N + col] = bf16r(v);
        else       ((float*)Cv)[(size_t)row * N + col] = v;
      }
    }
}

// ------- _process: read fp32 row, write bf16 row IN-PLACE (stride KSTR) -------
__global__ __launch_bounds__(256) void process_rows(float* __restrict__ X,
                                                    const float* __restrict__ sp) {
  const int row = blockIdx.x;
  const int tid = threadIdx.x;
  float* xr = X + (size_t)row * CD;
  float tv[3];
  float n2 = 0.f, m2 = 0.f;
  #pragma unroll
  for (int i = 0; i < 3; ++i) {
    int c = tid + i * 256;
    float t = fmaxf(xr[c], 0.f) + EPSF;
    t = t / sp[c];
    tv[i] = t;
    float t2 = t * t;
    n2 += t2;
    float p = t2 * t;
    m2 += p * p;
  }
  #pragma unroll
  for (int off = 32; off; off >>= 1) {
    n2 += __shfl_down(n2, off, 64);
    m2 += __shfl_down(m2, off, 64);
  }
  __shared__ float rn[4], rm[4];
  if ((tid & 63) == 0) { rn[tid >> 6] = n2; rm[tid >> 6] = m2; }
  __syncthreads();   // also orders: all global reads done before bf16 overwrite
  float N2 = rn[0] + rn[1] + rn[2] + rn[3];
  float M2 = rm[0] + rm[1] + rm[2] + rm[3];
  float factor = sqrtf(N2 / M2);   // = ||t|| / ||t^3||
  unsigned short* xo = (unsigned short*)xr;
  #pragma unroll
  for (int i = 0; i < 3; ++i) {
    int c = tid + i * 256;
    float t = tv[i];
    xo[c] = bf16r(t * t * t * factor);
  }
}

// ---- kv partials: kvp[ch][bh][d][e] = sum_{n in chunk} k[n,d]*v[n,e] --------
__global__ __launch_bounds__(256) void kv_part_k(const unsigned short* __restrict__ Kp,
                                                 const unsigned short* __restrict__ Vp,
                                                 float* __restrict__ kvp,
                                                 float* __restrict__ kmp) {
  const int bh = blockIdx.x, chunk = blockIdx.y;
  const int b = bh / NHEAD, h = bh % NHEAD;
  const int n0 = chunk * 128;
  __shared__ __align__(16) unsigned short ks[128 * 72];
  __shared__ __align__(16) unsigned short vs[128 * 72];
  const int tid = threadIdx.x;
  #pragma unroll
  for (int it = 0; it < 4; ++it) {
    int g = it * 256 + tid;            // 1024 groups of 8 elements per tile
    int row = g >> 3, c8 = (g & 7) * 8;
    int4 ka = *(const int4*)(Kp + ((size_t)(n0 + row) * BSZ + b) * KSTR + h * 64 + c8);
    int4 va = *(const int4*)(Vp + ((size_t)(n0 + row) * BSZ + b) * CD + h * 64 + c8);
    *(int4*)(ks + row * 72 + c8) = ka;
    *(int4*)(vs + row * 72 + c8) = va;
  }
  __syncthreads();
  const int d0 = (tid >> 4) * 4, e0 = (tid & 15) * 4;
  float acc[4][4] = {};
  #pragma unroll 4
  for (int n = 0; n < 128; ++n) {
    ushort4 kd = *(const ushort4*)(ks + n * 72 + d0);
    ushort4 ve = *(const ushort4*)(vs + n * 72 + e0);
    float kf[4] = {b2f(kd.x), b2f(kd.y), b2f(kd.z), b2f(kd.w)};
    float vf[4] = {b2f(ve.x), b2f(ve.y), b2f(ve.z), b2f(ve.w)};
    #pragma unroll
    for (int i = 0; i < 4; ++i)
      #pragma unroll
      for (int j = 0; j < 4; ++j) acc[i][j] += kf[i] * vf[j];
  }
  float* outp = kvp + ((size_t)chunk * 24 + bh) * 4096;
  #pragma unroll
  for (int i = 0; i < 4; ++i) {
    float4 o; o.x = acc[i][0]; o.y = acc[i][1]; o.z = acc[i][2]; o.w = acc[i][3];
    *(float4*)(outp + (d0 + i) * 64 + e0) = o;
  }
  if (tid < 64) {
    float s = 0.f;
    for (int n = 0; n < 128; ++n) s += b2f(ks[n * 72 + tid]);
    kmp[((size_t)chunk * 24 + bh) * 64 + tid] = s;
  }
}

// ---- reduce partials -> kvT[bh][e][d] bf16 (+1/Nm) and km[b][c] fp32 --------
__global__ __launch_bounds__(256) void kv_reduce_k(const float* __restrict__ kvp,
                                                   const float* __restrict__ kmp,
                                                   unsigned short* __restrict__ kvT,
                                                   float* __restrict__ km) {
  const int tid = threadIdx.x;
  const int bx = blockIdx.x;
  if (bx < 24) {
    __shared__ float t[64 * 65];
    float acc[16] = {};
    const float* base = kvp + (size_t)bx * 4096 + tid * 16;
    for (int c = 0; c < KVCH; ++c) {
      const float* p = base + (size_t)c * 24 * 4096;
      #pragma unroll
      for (int i = 0; i < 4; ++i) {
        float4 v = *(const float4*)(p + i * 4);
        acc[i * 4 + 0] += v.x; acc[i * 4 + 1] += v.y; acc[i * 4 + 2] += v.z; acc[i * 4 + 3] += v.w;
      }
    }
    const int d = tid >> 2, e0 = (tid & 3) * 16;   // writes row d, cols e0..e0+15
    #pragma unroll
    for (int i = 0; i < 16; ++i) t[d * 65 + e0 + i] = acc[i] * (1.f / NM_);
    __syncthreads();
    const int e = tid >> 2, dd0 = (tid & 3) * 16;  // read col e, rows dd0..+15
    ushort4 o[4];
    #pragma unroll
    for (int i = 0; i < 16; ++i)
      ((unsigned short*)o)[i] = bf16r(t[(dd0 + i) * 65 + e]);
    unsigned short* dst = kvT + (size_t)bx * 4096 + e * 64 + dd0;
    *(ushort4*)(dst) = o[0]; *(ushort4*)(dst + 4) = o[1];
    *(ushort4*)(dst + 8) = o[2]; *(ushort4*)(dst + 12) = o[3];
  } else {
    int i = (bx - 24) * 256 + tid;                 // 6 blocks cover 1536 outputs
    if (i < 24 * 64) {
      int bhh = i >> 6, d = i & 63;
      float s = 0.f;
      for (int c = 0; c < KVCH; ++c) s += kmp[((size_t)c * 24 + bhh) * 64 + d];
      int b = bhh / NHEAD, h = bhh % NHEAD;
      km[b * CD + h * 64 + d] = s * (1.f / NM_);
    }
  }
}

// -------- depthwise 5x5 conv, LDS-tiled: block = (b,h) x 16-wide x-tile ------
__global__ __launch_bounds__(256) void dwconv_k(const unsigned short* __restrict__ Vp,
                                                const float* __restrict__ w,
                                                const float* __restrict__ bias,
                                                unsigned short* __restrict__ outp) {
  __shared__ __align__(16) unsigned ls32[16 * 20 * 32];  // ushort2-packed channels
  __shared__ float wsm[64 * 25];
  __shared__ float bsm[64];
  const int tid = threadIdx.x;
  const int bh = blockIdx.x, b = bh / NHEAD, h = bh % NHEAD;
  const int x0 = blockIdx.y * 16;
  for (int i = tid; i < 1600; i += 256) wsm[i] = w[i];
  if (tid < 64) bsm[tid] = bias[tid];
  const int lch = (tid & 7) * 8;
  #pragma unroll
  for (int it = 0; it < 10; ++it) {
    int p = it * 32 + (tid >> 3);
    int y = p / 20, xp = p % 20;
    int xx = x0 + xp - 2;
    int4 val = {0, 0, 0, 0};
    if (xx >= 0 && xx < 256)
      val = *(const int4*)(Vp + ((size_t)((y << 8) + xx) * BSZ + b) * CD + h * 64 + lch);
    *(int4*)((unsigned short*)ls32 + p * 64 + lch) = val;
  }
  __syncthreads();
  const int cp = tid & 31;        // channel pair: ch = {2cp, 2cp+1}
  const int xs = tid >> 5;        // 0..7 -> x outputs {2xs, 2xs+1}
  float wr0[25], wr1[25];
  #pragma unroll
  for (int t = 0; t < 25; ++t) { wr0[t] = wsm[(cp * 2) * 25 + t]; wr1[t] = wsm[(cp * 2 + 1) * 25 + t]; }
  const float b0 = bsm[cp * 2], b1 = bsm[cp * 2 + 1];
  for (int y = 0; y < 16; ++y) {
    float a00 = b0, a01 = b1, a10 = b0, a11 = b1;
    #pragma unroll
    for (int dy = 0; dy < 5; ++dy) {
      int yy = y + dy - 2;
      if (yy < 0 || yy >= 16) continue;
      #pragma unroll
      for (int dx = 0; dx < 5; ++dx) {
        int base = (yy * 20 + xs * 2 + dx) * 32 + cp;
        unsigned u0 = ls32[base], u1 = ls32[base + 32];
        float w0 = wr0[dy * 5 + dx], w1 = wr1[dy * 5 + dx];
        a00 += w0 * asf(u0 << 16);  a01 += w1 * asf(u0 & 0xffff0000u);
        a10 += w0 * asf(u1 << 16);  a11 += w1 * asf(u1 & 0xffff0000u);
      }
    }
    const int x = x0 + xs * 2;
    size_t o = ((size_t)((y << 8) + x) * BSZ + b) * CD + h * 64 + cp * 2;
    ushort2 s0; s0.x = bf16r(a00); s0.y = bf16r(a01);
    ushort2 s1; s1.x = bf16r(a10); s1.y = bf16r(a11);
    *(ushort2*)(outp + o) = s0;
    *(ushort2*)(outp + o + (size_t)BSZ * CD) = s1;
  }
}

// ------ attn: tmp = bf16( z * (q @ kv) + dwc ), MFMA per head, K=64 ---------
__global__ __launch_bounds__(256) void attn_mfma(const unsigned short* __restrict__ Qb,
                                                 const unsigned short* __restrict__ kvT,
                                                 const float* __restrict__ km,
                                                 const unsigned short* __restrict__ dwcb,
                                                 unsigned short* __restrict__ tmpb) {
  __shared__ __align__(16) unsigned short qs[128 * 64];
  __shared__ __align__(16) unsigned short kvs[64 * 64];
  __shared__ float kms[64];
  __shared__ float zs[128];
  const int bh = blockIdx.x, b = bh / NHEAD, h = bh % NHEAD;
  const int n0 = blockIdx.y * 128;
  const int tid = threadIdx.x, wave = tid >> 6, lane = tid & 63;
  const int quad = lane >> 4, l16 = lane & 15;
  #pragma unroll
  for (int c2 = 0; c2 < 4; ++c2) {
    int ch = wave * 4 + c2;
    int row = ch * 8 + (lane >> 3);
    int col = (lane & 7) * 8;
    gl2lds16(Qb + ((size_t)(n0 + row) * BSZ + b) * KSTR + h * 64 + col, (void*)(qs + ch * 512));
  }
  #pragma unroll
  for (int c2 = 0; c2 < 2; ++c2) {
    int ch = wave * 2 + c2;
    int e = ch * 8 + (lane >> 3);
    int col = (lane & 7) * 8;
    gl2lds16(kvT + (size_t)bh * 4096 + e * 64 + col, (void*)(kvs + ch * 512));
  }
  if (tid < 64) kms[tid] = km[b * CD + h * 64 + tid];
  __syncthreads();
  if (tid < 128) {
    float s = 0.f;
    for (int d2 = 0; d2 < 64; ++d2) s += b2f(qs[tid * 64 + d2]) * kms[d2];
    zs[tid] = 1.f / (s + EPSF);
  }
  __syncthreads();
  f32x4 acc[2][4] = {};
  #pragma unroll
  for (int kh = 0; kh < 2; ++kh) {
    bf16x8 a0 = *(const bf16x8*)(qs + (wave * 32 + l16) * 64 + kh * 32 + quad * 8);
    bf16x8 a1 = *(const bf16x8*)(qs + (wave * 32 + 16 + l16) * 64 + kh * 32 + quad * 8);
    bf16x8 bt[4];
    #pragma unroll
    for (int tn = 0; tn < 4; ++tn)
      bt[tn] = *(const bf16x8*)(kvs + (tn * 16 + l16) * 64 + kh * 32 + quad * 8);
    #pragma unroll
    for (int tn = 0; tn < 4; ++tn) {
      acc[0][tn] = __builtin_amdgcn_mfma_f32_16x16x32_bf16(a0, bt[tn], acc[0][tn], 0, 0, 0);
      acc[1][tn] = __builtin_amdgcn_mfma_f32_16x16x32_bf16(a1, bt[tn], acc[1][tn], 0, 0, 0);
    }
  }
  #pragma unroll
  for (int tm = 0; tm < 2; ++tm)
    #pragma unroll
    for (int tn = 0; tn < 4; ++tn)
      #pragma unroll
      for (int r = 0; r < 4; ++r) {
        int rl = wave * 32 + tm * 16 + quad * 4 + r;
        int n = n0 + rl;
        int m = n & (NM_ - 1);
        int c = h * 64 + tn * 16 + l16;
        float val = acc[tm][tn][r] * zs[rl] + b2f(dwcb[((size_t)m * BSZ + b) * CD + c]);
        tmpb[((size_t)n * BSZ + b) * CD + c] = bf16r(val);
      }
}

// =============================== launcher ===============================
extern "C" void kernel_launch(void* const* d_in, const int* in_sizes, int n_in,
                              void* d_out, int out_size, void* d_ws, size_t ws_size,
                              hipStream_t stream) {
  const float* x      = (const float*)d_in[0];
  const float* memory = (const float*)d_in[1];
  const float* w_q    = (const float*)d_in[2];
  const float* w_k    = (const float*)d_in[3];
  const float* w_v    = (const float*)d_in[4];
  const float* w_proj = (const float*)d_in[5];
  const float* b_proj = (const float*)d_in[6];
  const float* dwc_w  = (const float*)d_in[7];
  const float* dwc_b  = (const float*)d_in[8];
  const float* scale  = (const float*)d_in[9];
  float* out = (float*)d_out;

  const int Mq = NX_ * BSZ;   // 32768
  const int Mm = NM_ * BSZ;   // 8192

  char* ws = (char*)d_ws;
  size_t off = 0;
  auto alloc = [&](size_t bytes) -> void* {
    void* p = ws + off;
    off += (bytes + 255) & ~(size_t)255;
    return p;
  };
  float* q    = (float*)alloc((size_t)Mq * CD * 4);   // fp32, later bf16 in-place (stride KSTR)
  float* kbuf = (float*)alloc((size_t)Mm * CD * 4);   // fp32, later bf16 in-place
  float* kvp  = (float*)alloc((size_t)KVCH * 24 * 4096 * 4);   // 12.6 MB partials
  float* kmp  = (float*)alloc((size_t)KVCH * 24 * 64 * 4);
  float* km   = (float*)alloc((size_t)BSZ * CD * 4);
  float* sp   = (float*)alloc(CD * 4);
  unsigned short* tmpb = (unsigned short*)alloc((size_t)Mq * CD * 2);
  unsigned short* vb   = (unsigned short*)alloc((size_t)Mm * CD * 2);  // bf16 v
  unsigned short* dwcb = (unsigned short*)alloc((size_t)Mm * CD * 2);
  unsigned short* kvT  = (unsigned short*)alloc((size_t)BSZ * NHEAD * DH * DH * 2);
  unsigned short* wqb  = (unsigned short*)alloc((size_t)CD * CD * 2);
  unsigned short* wkb  = (unsigned short*)alloc((size_t)CD * CD * 2);
  unsigned short* wvb  = (unsigned short*)alloc((size_t)CD * CD * 2);
  unsigned short* wpb  = (unsigned short*)alloc((size_t)CD * CD * 2);

  // buffer reuse (lifetimes checked): xb lives in tmpb until attn_mfma writes it;
  // memb lives in dwcb until dwconv_k writes it (k/v gemms read memb before that).
  unsigned short* xb   = tmpb;
  unsigned short* memb = dwcb;

  prep_k<<<2307, 256, 0, stream>>>(w_q, w_k, w_v, w_proj, scale, wqb, wkb, wvb, wpb, sp);

  cvt_k<<<(Mq * CD / 8 + 255) / 256, 256, 0, stream>>>(x, xb, Mq * CD / 8);
  cvt_k<<<(Mm * CD / 8 + 255) / 256, 256, 0, stream>>>(memory, memb, Mm * CD / 8);

  gemm256<0><<<dim3(Mq / 256, CD / 256), 512, 0, stream>>>(xb,   wqb, q,    nullptr, Mq, CD, CD);
  gemm128<0><<<dim3(Mm / 128, CD / 128), 256, 0, stream>>>(memb, wkb, kbuf, nullptr, Mm, CD, CD);
  gemm128<1><<<dim3(Mm / 128, CD / 128), 256, 0, stream>>>(memb, wvb, vb,   nullptr, Mm, CD, CD);

  process_rows<<<Mq, 256, 0, stream>>>(q, sp);     // q -> bf16 in-place
  process_rows<<<Mm, 256, 0, stream>>>(kbuf, sp);  // k -> bf16 in-place

  const unsigned short* qb = (const unsigned short*)q;
  const unsigned short* kb = (const unsigned short*)kbuf;

  kv_part_k<<<dim3(24, KVCH), 256, 0, stream>>>(kb, vb, kvp, kmp);
  kv_reduce_k<<<30, 256, 0, stream>>>(kvp, kmp, kvT, km);

  dwconv_k<<<dim3(BSZ * NHEAD, 16), 256, 0, stream>>>(vb, dwc_w, dwc_b, dwcb);

  attn_mfma<<<dim3(BSZ * NHEAD, NX_ / 128), 256, 0, stream>>>(qb, kvT, km, dwcb, tmpb);

  gemm256<0><<<dim3(Mq / 256, CD / 256), 512, 0, stream>>>(tmpb, wpb, out, b_proj, Mq, CD, CD);
}

// Round 5
// 510.496 us; speedup vs baseline: 1.0350x; 1.0077x over previous
//
#include <hip/hip_runtime.h>

#define CD 768
#define NHEAD 12
#define DH 64
#define BSZ 2
#define NM_ 4096
#define NX_ 16384
#define EPSF 1e-6f
#define KSTR 1536   // ushort stride of in-place bf16 rows inside an fp32 buffer
#define KVCH 32     // split-K chunks for kv partials

using bf16x8 = __attribute__((ext_vector_type(8))) short;
using f32x4  = __attribute__((ext_vector_type(4))) float;

__device__ inline unsigned short bf16r(float f) {
  union { float f; unsigned u; } un; un.f = f;
  unsigned u = un.u;
  u += 0x7fffu + ((u >> 16) & 1u);
  return (unsigned short)(u >> 16);
}
__device__ inline float b2f(unsigned short u) {
  union { unsigned u; float f; } x; x.u = ((unsigned)u) << 16; return x.f;
}
__device__ inline float asf(unsigned u) {
  union { unsigned u; float f; } x; x.u = u; return x.f;
}
// async global->LDS, 16B per lane; LDS dest = wave-uniform base + lane*16
__device__ inline void gl2lds16(const void* g, void* l) {
  __builtin_amdgcn_global_load_lds(
      (const __attribute__((address_space(1))) void*)g,
      (__attribute__((address_space(3))) void*)l, 16, 0, 0);
}

// ---- prep: 4 weight matrices fp32->bf16 + softplus(scale), ONE dispatch ----
__global__ __launch_bounds__(256) void prep_k(const float* __restrict__ w0, const float* __restrict__ w1,
                                              const float* __restrict__ w2, const float* __restrict__ w3,
                                              const float* __restrict__ scale,
                                              unsigned short* __restrict__ o0, unsigned short* __restrict__ o1,
                                              unsigned short* __restrict__ o2, unsigned short* __restrict__ o3,
                                              float* __restrict__ sp) {
  int bx = blockIdx.x;
  if (bx < 2304) {                    // 4 matrices x 576 blocks x 256 float4
    int m = bx / 576;
    int i = (bx % 576) * 256 + threadIdx.x;
    const float* w = m == 0 ? w0 : m == 1 ? w1 : m == 2 ? w2 : w3;
    unsigned short* o = m == 0 ? o0 : m == 1 ? o1 : m == 2 ? o2 : o3;
    float4 v = ((const float4*)w)[i];
    ushort4 u; u.x = bf16r(v.x); u.y = bf16r(v.y); u.z = bf16r(v.z); u.w = bf16r(v.w);
    ((ushort4*)o)[i] = u;
  } else {
    int i = (bx - 2304) * 256 + threadIdx.x;
    if (i < CD) sp[i] = log1pf(expf(scale[i]));
  }
}

// ---- fp32 -> bf16 bulk convert: thread i converts 8 elements (32B in, 16B out)
__global__ __launch_bounds__(256) void cvt_k(const float* __restrict__ s,
                                             unsigned short* __restrict__ d, int n8) {
  int i = blockIdx.x * 256 + threadIdx.x;
  if (i >= n8) return;
  const float4* sp = (const float4*)s;
  float4 f0 = sp[(size_t)i * 2], f1 = sp[(size_t)i * 2 + 1];
  unsigned short u[8];
  u[0] = bf16r(f0.x); u[1] = bf16r(f0.y); u[2] = bf16r(f0.z); u[3] = bf16r(f0.w);
  u[4] = bf16r(f1.x); u[5] = bf16r(f1.y); u[6] = bf16r(f1.z); u[7] = bf16r(f1.w);
  *(int4*)(d + (size_t)i * 8) = *(int4*)u;
}

// ------- 128x128-tile GEMM (bf16 A): C[M,N] = A[M,K] @ B[N,K]^T (+bias) -----
template<int OUTBF>
__global__ __launch_bounds__(256) void gemm128(const unsigned short* __restrict__ A,
                                               const unsigned short* __restrict__ B,
                                               void* __restrict__ Cv,
                                               const float* __restrict__ bias,
                                               int M, int N, int K) {
  __shared__ __align__(16) unsigned short As[128 * 32];
  __shared__ __align__(16) unsigned short Bs[128 * 32];
  const int m0 = blockIdx.x * 128, n0 = blockIdx.y * 128;
  const int tid = threadIdx.x, wave = tid >> 6, lane = tid & 63;
  const int quad = lane >> 4, l16 = lane & 15;
  const int wm = (wave >> 1) * 64, wn = (wave & 1) * 64;
  const int srow = lane >> 2, scol = (lane & 3) * 8;  // gl2lds: 16 rows/chunk, 4 lanes/row
  f32x4 acc[4][4] = {};
  for (int k0 = 0; k0 < K; k0 += 32) {
    __syncthreads();
    #pragma unroll
    for (int c2 = 0; c2 < 2; ++c2) {
      int ch = wave * 2 + c2;
      gl2lds16(A + (size_t)(m0 + ch * 16 + srow) * K + k0 + scol, (void*)(As + ch * 512));
      gl2lds16(B + (size_t)(n0 + ch * 16 + srow) * K + k0 + scol, (void*)(Bs + ch * 512));
    }
    __syncthreads();
    bf16x8 a[4], bb[4];
    #pragma unroll
    for (int t = 0; t < 4; ++t) {
      a[t]  = *(const bf16x8*)(As + (wm + t * 16 + l16) * 32 + quad * 8);
      bb[t] = *(const bf16x8*)(Bs + (wn + t * 16 + l16) * 32 + quad * 8);
    }
    #pragma unroll
    for (int tm = 0; tm < 4; ++tm)
      #pragma unroll
      for (int tn = 0; tn < 4; ++tn)
        acc[tm][tn] = __builtin_amdgcn_mfma_f32_16x16x32_bf16(a[tm], bb[tn], acc[tm][tn], 0, 0, 0);
  }
  // D layout: col = lane&15, row = quad*4 + r  [m89/m91 verified]
  #pragma unroll
  for (int tm = 0; tm < 4; ++tm)
    #pragma unroll
    for (int tn = 0; tn < 4; ++tn) {
      const int col = n0 + wn + tn * 16 + l16;
      const float bv = bias ? bias[col] : 0.f;
      #pragma unroll
      for (int r = 0; r < 4; ++r) {
        const int row = m0 + wm + tm * 16 + quad * 4 + r;
        float v = acc[tm][tn][r] + bv;
        if (OUTBF) ((unsigned short*)Cv)[(size_t)row * N + col] = bf16r(v);
        else       ((float*)Cv)[(size_t)row * N + col] = v;
      }
    }
}

// ====== 256x192-tile ring-3 GEMM, K=768: C[M,768] = A[M,768] @ B[768,768]^T ==
// 1024 threads = 16 waves (4m x 4n); per-wave 64x48 out = acc[4][3] (48 VGPR).
// Ring-3 double... triple-buffer with SIX DISTINCT __shared__ objects and a
// 3x-unrolled slice loop so every gl2lds dest / ds_read src is a compile-time
// object -> alias analysis keeps counted vmcnt(2) honest (no spurious drains).
// One barrier/slice: stage(s+2) overwrites the slot consumed in slice s-1,
// which the top-of-slice-s barrier proves complete. 2 gl2lds + 7 ds_read +
// 12 MFMA per wave-slice. Grid (M/256, 4): Mq -> 512 blocks = exactly 2 gens.
// LDS XOR-swizzle as before (measured 0 conflicts).
template<int OUTBF>
__global__ __launch_bounds__(1024, 4) void gemm256c(const unsigned short* __restrict__ A,
                                                    const unsigned short* __restrict__ B,
                                                    void* __restrict__ Cv,
                                                    const float* __restrict__ bias,
                                                    int M, int N) {
  __shared__ __align__(16) unsigned short As0[8192], As1[8192], As2[8192];  // 256x32 each
  __shared__ __align__(16) unsigned short Bs0[8192], Bs1[8192], Bs2[8192];  // 192x32 + pad
  const int m0 = blockIdx.x * 256, n0 = blockIdx.y * 192;
  const int tid = threadIdx.x, w = tid >> 6, lane = tid & 63;
  const int quad = lane >> 4, l16 = lane & 15;
  const int wm = (w >> 2) * 64, wn = (w & 3) * 48;
  const int fq = (quad ^ ((l16 >> 1) & 3)) * 8;
  const int lrow = lane >> 2, lc = lane & 3;
  f32x4 acc[4][3] = {};

  // chunks: 32 x 1KB per slice. c<16: A rows c*16..+16. 16<=c<28: B rows
  // (c-16)*16. c>=28: duplicate B rows 0..63 into Bs pad (keeps load count
  // uniform: every wave issues exactly 2 gl2lds/slice -> vmcnt math uniform).
  auto stage = [&](int s, unsigned short* la, unsigned short* lb) {
    const int kc = s * 32;
    #pragma unroll
    for (int j = 0; j < 2; ++j) {
      const int c = w * 2 + j;
      if (c < 16) {
        const int grow = c * 16 + lrow;
        const int gcol = (lc ^ ((grow >> 1) & 3)) * 8;
        gl2lds16(A + (size_t)(m0 + grow) * 768 + kc + gcol, (void*)(la + c * 512));
      } else {
        const int bc = (c < 28) ? c - 16 : c - 28;
        const int grow = bc * 16 + lrow;
        const int gcol = (lc ^ ((grow >> 1) & 3)) * 8;
        gl2lds16(B + (size_t)(n0 + grow) * 768 + kc + gcol, (void*)(lb + (c - 16) * 512));
      }
    }
  };

  auto body = [&](int s, const unsigned short* sa, const unsigned short* sb,
                  unsigned short* na, unsigned short* nb) {
    if (s < 23) asm volatile("s_waitcnt vmcnt(2)");   // retire slice s, keep s+1
    else        asm volatile("s_waitcnt vmcnt(0)");
    __builtin_amdgcn_s_barrier();   // slot-s data visible; slot-(s-1) fully consumed
    bf16x8 av[4], bv[3];
    #pragma unroll
    for (int f = 0; f < 4; ++f)
      av[f] = *(const bf16x8*)(sa + (wm + f * 16 + l16) * 32 + fq);
    #pragma unroll
    for (int nf = 0; nf < 3; ++nf)
      bv[nf] = *(const bf16x8*)(sb + (wn + nf * 16 + l16) * 32 + fq);
    if (s + 2 < 24) stage(s + 2, na, nb);             // overwrites slot (s-1): safe
    __builtin_amdgcn_s_setprio(1);
    #pragma unroll
    for (int mf = 0; mf < 4; ++mf)
      #pragma unroll
      for (int nf = 0; nf < 3; ++nf)
        acc[mf][nf] = __builtin_amdgcn_mfma_f32_16x16x32_bf16(av[mf], bv[nf], acc[mf][nf], 0, 0, 0);
    __builtin_amdgcn_s_setprio(0);
  };

  stage(0, As0, Bs0);
  stage(1, As1, Bs1);
  for (int su = 0; su < 24; su += 3) {
    body(su,     As0, Bs0, As2, Bs2);
    body(su + 1, As1, Bs1, As0, Bs0);
    body(su + 2, As2, Bs2, As1, Bs1);
  }
  // D layout: col = lane&15, row = quad*4 + r  [m89/m91 verified]
  #pragma unroll
  for (int mf = 0; mf < 4; ++mf)
    #pragma unroll
    for (int nf = 0; nf < 3; ++nf) {
      const int col = n0 + wn + nf * 16 + l16;
      const float bvl = bias ? bias[col] : 0.f;
      #pragma unroll
      for (int r = 0; r < 4; ++r) {
        const int row = m0 + wm + mf * 16 + quad * 4 + r;
        float v = acc[mf][nf][r] + bvl;
        if (OUTBF) ((unsigned short*)Cv)[(size_t)row * N + col] = bf16r(v);
        else       ((float*)Cv)[(size_t)row * N + col] = v;
      }
    }
}

// ------- _process: read fp32 row, write bf16 row IN-PLACE (stride KSTR) -------
__global__ __launch_bounds__(256) void process_rows(float* __restrict__ X,
                                                    const float* __restrict__ sp) {
  const int row = blockIdx.x;
  const int tid = threadIdx.x;
  float* xr = X + (size_t)row * CD;
  float tv[3];
  float n2 = 0.f, m2 = 0.f;
  #pragma unroll
  for (int i = 0; i < 3; ++i) {
    int c = tid + i * 256;
    float t = fmaxf(xr[c], 0.f) + EPSF;
    t = t / sp[c];
    tv[i] = t;
    float t2 = t * t;
    n2 += t2;
    float p = t2 * t;
    m2 += p * p;
  }
  #pragma unroll
  for (int off = 32; off; off >>= 1) {
    n2 += __shfl_down(n2, off, 64);
    m2 += __shfl_down(m2, off, 64);
  }
  __shared__ float rn[4], rm[4];
  if ((tid & 63) == 0) { rn[tid >> 6] = n2; rm[tid >> 6] = m2; }
  __syncthreads();   // also orders: all global reads done before bf16 overwrite
  float N2 = rn[0] + rn[1] + rn[2] + rn[3];
  float M2 = rm[0] + rm[1] + rm[2] + rm[3];
  float factor = sqrtf(N2 / M2);   // = ||t|| / ||t^3||
  unsigned short* xo = (unsigned short*)xr;
  #pragma unroll
  for (int i = 0; i < 3; ++i) {
    int c = tid + i * 256;
    float t = tv[i];
    xo[c] = bf16r(t * t * t * factor);
  }
}

// ---- kv partials: kvp[ch][bh][d][e] = sum_{n in chunk} k[n,d]*v[n,e] --------
__global__ __launch_bounds__(256) void kv_part_k(const unsigned short* __restrict__ Kp,
                                                 const unsigned short* __restrict__ Vp,
                                                 float* __restrict__ kvp,
                                                 float* __restrict__ kmp) {
  const int bh = blockIdx.x, chunk = blockIdx.y;
  const int b = bh / NHEAD, h = bh % NHEAD;
  const int n0 = chunk * 128;
  __shared__ __align__(16) unsigned short ks[128 * 72];
  __shared__ __align__(16) unsigned short vs[128 * 72];
  const int tid = threadIdx.x;
  #pragma unroll
  for (int it = 0; it < 4; ++it) {
    int g = it * 256 + tid;            // 1024 groups of 8 elements per tile
    int row = g >> 3, c8 = (g & 7) * 8;
    int4 ka = *(const int4*)(Kp + ((size_t)(n0 + row) * BSZ + b) * KSTR + h * 64 + c8);
    int4 va = *(const int4*)(Vp + ((size_t)(n0 + row) * BSZ + b) * CD + h * 64 + c8);
    *(int4*)(ks + row * 72 + c8) = ka;
    *(int4*)(vs + row * 72 + c8) = va;
  }
  __syncthreads();
  const int d0 = (tid >> 4) * 4, e0 = (tid & 15) * 4;
  float acc[4][4] = {};
  #pragma unroll 4
  for (int n = 0; n < 128; ++n) {
    ushort4 kd = *(const ushort4*)(ks + n * 72 + d0);
    ushort4 ve = *(const ushort4*)(vs + n * 72 + e0);
    float kf[4] = {b2f(kd.x), b2f(kd.y), b2f(kd.z), b2f(kd.w)};
    float vf[4] = {b2f(ve.x), b2f(ve.y), b2f(ve.z), b2f(ve.w)};
    #pragma unroll
    for (int i = 0; i < 4; ++i)
      #pragma unroll
      for (int j = 0; j < 4; ++j) acc[i][j] += kf[i] * vf[j];
  }
  float* outp = kvp + ((size_t)chunk * 24 + bh) * 4096;
  #pragma unroll
  for (int i = 0; i < 4; ++i) {
    float4 o; o.x = acc[i][0]; o.y = acc[i][1]; o.z = acc[i][2]; o.w = acc[i][3];
    *(float4*)(outp + (d0 + i) * 64 + e0) = o;
  }
  if (tid < 64) {
    float s = 0.f;
    for (int n = 0; n < 128; ++n) s += b2f(ks[n * 72 + tid]);
    kmp[((size_t)chunk * 24 + bh) * 64 + tid] = s;
  }
}

// ---- reduce partials -> kvT[bh][e][d] bf16 (+1/Nm) and km[b][c] fp32 --------
__global__ __launch_bounds__(256) void kv_reduce_k(const float* __restrict__ kvp,
                                                   const float* __restrict__ kmp,
                                                   unsigned short* __restrict__ kvT,
                                                   float* __restrict__ km) {
  const int tid = threadIdx.x;
  const int bx = blockIdx.x;
  if (bx < 24) {
    __shared__ float t[64 * 65];
    float acc[16] = {};
    const float* base = kvp + (size_t)bx * 4096 + tid * 16;
    for (int c = 0; c < KVCH; ++c) {
      const float* p = base + (size_t)c * 24 * 4096;
      #pragma unroll
      for (int i = 0; i < 4; ++i) {
        float4 v = *(const float4*)(p + i * 4);
        acc[i * 4 + 0] += v.x; acc[i * 4 + 1] += v.y; acc[i * 4 + 2] += v.z; acc[i * 4 + 3] += v.w;
      }
    }
    const int d = tid >> 2, e0 = (tid & 3) * 16;   // writes row d, cols e0..e0+15
    #pragma unroll
    for (int i = 0; i < 16; ++i) t[d * 65 + e0 + i] = acc[i] * (1.f / NM_);
    __syncthreads();
    const int e = tid >> 2, dd0 = (tid & 3) * 16;  // read col e, rows dd0..+15
    ushort4 o[4];
    #pragma unroll
    for (int i = 0; i < 16; ++i)
      ((unsigned short*)o)[i] = bf16r(t[(dd0 + i) * 65 + e]);
    unsigned short* dst = kvT + (size_t)bx * 4096 + e * 64 + dd0;
    *(ushort4*)(dst) = o[0]; *(ushort4*)(dst + 4) = o[1];
    *(ushort4*)(dst + 8) = o[2]; *(ushort4*)(dst + 12) = o[3];
  } else {
    int i = (bx - 24) * 256 + tid;                 // 6 blocks cover 1536 outputs
    if (i < 24 * 64) {
      int bhh = i >> 6, d = i & 63;
      float s = 0.f;
      for (int c = 0; c < KVCH; ++c) s += kmp[((size_t)c * 24 + bhh) * 64 + d];
      int b = bhh / NHEAD, h = bhh % NHEAD;
      km[b * CD + h * 64 + d] = s * (1.f / NM_);
    }
  }
}

// -------- depthwise 5x5 conv, LDS-tiled: block = (b,h) x 16-wide x-tile ------
__global__ __launch_bounds__(256) void dwconv_k(const unsigned short* __restrict__ Vp,
                                                const float* __restrict__ w,
                                                const float* __restrict__ bias,
                                                unsigned short* __restrict__ outp) {
  __shared__ __align__(16) unsigned ls32[16 * 20 * 32];  // ushort2-packed channels
  __shared__ float wsm[64 * 25];
  __shared__ float bsm[64];
  const int tid = threadIdx.x;
  const int bh = blockIdx.x, b = bh / NHEAD, h = bh % NHEAD;
  const int x0 = blockIdx.y * 16;
  for (int i = tid; i < 1600; i += 256) wsm[i] = w[i];
  if (tid < 64) bsm[tid] = bias[tid];
  const int lch = (tid & 7) * 8;
  #pragma unroll
  for (int it = 0; it < 10; ++it) {
    int p = it * 32 + (tid >> 3);
    int y = p / 20, xp = p % 20;
    int xx = x0 + xp - 2;
    int4 val = {0, 0, 0, 0};
    if (xx >= 0 && xx < 256)
      val = *(const int4*)(Vp + ((size_t)((y << 8) + xx) * BSZ + b) * CD + h * 64 + lch);
    *(int4*)((unsigned short*)ls32 + p * 64 + lch) = val;
  }
  __syncthreads();
  const int cp = tid & 31;        // channel pair: ch = {2cp, 2cp+1}
  const int xs = tid >> 5;        // 0..7 -> x outputs {2xs, 2xs+1}
  float wr0[25], wr1[25];
  #pragma unroll
  for (int t = 0; t < 25; ++t) { wr0[t] = wsm[(cp * 2) * 25 + t]; wr1[t] = wsm[(cp * 2 + 1) * 25 + t]; }
  const float b0 = bsm[cp * 2], b1 = bsm[cp * 2 + 1];
  for (int y = 0; y < 16; ++y) {
    float a00 = b0, a01 = b1, a10 = b0, a11 = b1;
    #pragma unroll
    for (int dy = 0; dy < 5; ++dy) {
      int yy = y + dy - 2;
      if (yy < 0 || yy >= 16) continue;
      #pragma unroll
      for (int dx = 0; dx < 5; ++dx) {
        int base = (yy * 20 + xs * 2 + dx) * 32 + cp;
        unsigned u0 = ls32[base], u1 = ls32[base + 32];
        float w0 = wr0[dy * 5 + dx], w1 = wr1[dy * 5 + dx];
        a00 += w0 * asf(u0 << 16);  a01 += w1 * asf(u0 & 0xffff0000u);
        a10 += w0 * asf(u1 << 16);  a11 += w1 * asf(u1 & 0xffff0000u);
      }
    }
    const int x = x0 + xs * 2;
    size_t o = ((size_t)((y << 8) + x) * BSZ + b) * CD + h * 64 + cp * 2;
    ushort2 s0; s0.x = bf16r(a00); s0.y = bf16r(a01);
    ushort2 s1; s1.x = bf16r(a10); s1.y = bf16r(a11);
    *(ushort2*)(outp + o) = s0;
    *(ushort2*)(outp + o + (size_t)BSZ * CD) = s1;
  }
}

// ------ attn: tmp = bf16( z * (q @ kv) + dwc ), MFMA per head, K=64 ---------
__global__ __launch_bounds__(256) void attn_mfma(const unsigned short* __restrict__ Qb,
                                                 const unsigned short* __restrict__ kvT,
                                                 const float* __restrict__ km,
                                                 const unsigned short* __restrict__ dwcb,
                                                 unsigned short* __restrict__ tmpb) {
  __shared__ __align__(16) unsigned short qs[128 * 64];
  __shared__ __align__(16) unsigned short kvs[64 * 64];
  __shared__ float kms[64];
  __shared__ float zs[128];
  const int bh = blockIdx.x, b = bh / NHEAD, h = bh % NHEAD;
  const int n0 = blockIdx.y * 128;
  const int tid = threadIdx.x, wave = tid >> 6, lane = tid & 63;
  const int quad = lane >> 4, l16 = lane & 15;
  #pragma unroll
  for (int c2 = 0; c2 < 4; ++c2) {
    int ch = wave * 4 + c2;
    int row = ch * 8 + (lane >> 3);
    int col = (lane & 7) * 8;
    gl2lds16(Qb + ((size_t)(n0 + row) * BSZ + b) * KSTR + h * 64 + col, (void*)(qs + ch * 512));
  }
  #pragma unroll
  for (int c2 = 0; c2 < 2; ++c2) {
    int ch = wave * 2 + c2;
    int e = ch * 8 + (lane >> 3);
    int col = (lane & 7) * 8;
    gl2lds16(kvT + (size_t)bh * 4096 + e * 64 + col, (void*)(kvs + ch * 512));
  }
  if (tid < 64) kms[tid] = km[b * CD + h * 64 + tid];
  __syncthreads();
  if (tid < 128) {
    float s = 0.f;
    for (int d2 = 0; d2 < 64; ++d2) s += b2f(qs[tid * 64 + d2]) * kms[d2];
    zs[tid] = 1.f / (s + EPSF);
  }
  __syncthreads();
  f32x4 acc[2][4] = {};
  #pragma unroll
  for (int kh = 0; kh < 2; ++kh) {
    bf16x8 a0 = *(const bf16x8*)(qs + (wave * 32 + l16) * 64 + kh * 32 + quad * 8);
    bf16x8 a1 = *(const bf16x8*)(qs + (wave * 32 + 16 + l16) * 64 + kh * 32 + quad * 8);
    bf16x8 bt[4];
    #pragma unroll
    for (int tn = 0; tn < 4; ++tn)
      bt[tn] = *(const bf16x8*)(kvs + (tn * 16 + l16) * 64 + kh * 32 + quad * 8);
    #pragma unroll
    for (int tn = 0; tn < 4; ++tn) {
      acc[0][tn] = __builtin_amdgcn_mfma_f32_16x16x32_bf16(a0, bt[tn], acc[0][tn], 0, 0, 0);
      acc[1][tn] = __builtin_amdgcn_mfma_f32_16x16x32_bf16(a1, bt[tn], acc[1][tn], 0, 0, 0);
    }
  }
  #pragma unroll
  for (int tm = 0; tm < 2; ++tm)
    #pragma unroll
    for (int tn = 0; tn < 4; ++tn)
      #pragma unroll
      for (int r = 0; r < 4; ++r) {
        int rl = wave * 32 + tm * 16 + quad * 4 + r;
        int n = n0 + rl;
        int m = n & (NM_ - 1);
        int c = h * 64 + tn * 16 + l16;
        float val = acc[tm][tn][r] * zs[rl] + b2f(dwcb[((size_t)m * BSZ + b) * CD + c]);
        tmpb[((size_t)n * BSZ + b) * CD + c] = bf16r(val);
      }
}

// =============================== launcher ===============================
extern "C" void kernel_launch(void* const* d_in, const int* in_sizes, int n_in,
                              void* d_out, int out_size, void* d_ws, size_t ws_size,
                              hipStream_t stream) {
  const float* x      = (const float*)d_in[0];
  const float* memory = (const float*)d_in[1];
  const float* w_q    = (const float*)d_in[2];
  const float* w_k    = (const float*)d_in[3];
  const float* w_v    = (const float*)d_in[4];
  const float* w_proj = (const float*)d_in[5];
  const float* b_proj = (const float*)d_in[6];
  const float* dwc_w  = (const float*)d_in[7];
  const float* dwc_b  = (const float*)d_in[8];
  const float* scale  = (const float*)d_in[9];
  float* out = (float*)d_out;

  const int Mq = NX_ * BSZ;   // 32768
  const int Mm = NM_ * BSZ;   // 8192

  char* ws = (char*)d_ws;
  size_t off = 0;
  auto alloc = [&](size_t bytes) -> void* {
    void* p = ws + off;
    off += (bytes + 255) & ~(size_t)255;
    return p;
  };
  float* q    = (float*)alloc((size_t)Mq * CD * 4);   // fp32, later bf16 in-place (stride KSTR)
  float* kbuf = (float*)alloc((size_t)Mm * CD * 4);   // fp32, later bf16 in-place
  float* kvp  = (float*)alloc((size_t)KVCH * 24 * 4096 * 4);   // 12.6 MB partials
  float* kmp  = (float*)alloc((size_t)KVCH * 24 * 64 * 4);
  float* km   = (float*)alloc((size_t)BSZ * CD * 4);
  float* sp   = (float*)alloc(CD * 4);
  unsigned short* tmpb = (unsigned short*)alloc((size_t)Mq * CD * 2);
  unsigned short* vb   = (unsigned short*)alloc((size_t)Mm * CD * 2);  // bf16 v
  unsigned short* dwcb = (unsigned short*)alloc((size_t)Mm * CD * 2);
  unsigned short* kvT  = (unsigned short*)alloc((size_t)BSZ * NHEAD * DH * DH * 2);
  unsigned short* wqb  = (unsigned short*)alloc((size_t)CD * CD * 2);
  unsigned short* wkb  = (unsigned short*)alloc((size_t)CD * CD * 2);
  unsigned short* wvb  = (unsigned short*)alloc((size_t)CD * CD * 2);
  unsigned short* wpb  = (unsigned short*)alloc((size_t)CD * CD * 2);

  // buffer reuse (lifetimes checked): xb lives in tmpb until attn_mfma writes it;
  // memb lives in dwcb until dwconv_k writes it (k/v gemms read memb before that).
  unsigned short* xb   = tmpb;
  unsigned short* memb = dwcb;

  prep_k<<<2307, 256, 0, stream>>>(w_q, w_k, w_v, w_proj, scale, wqb, wkb, wvb, wpb, sp);

  cvt_k<<<(Mq * CD / 8 + 255) / 256, 256, 0, stream>>>(x, xb, Mq * CD / 8);
  cvt_k<<<(Mm * CD / 8 + 255) / 256, 256, 0, stream>>>(memory, memb, Mm * CD / 8);

  gemm256c<0><<<dim3(Mq / 256, 4), 1024, 0, stream>>>(xb,   wqb, q,    nullptr, Mq, CD);
  gemm128<0><<<dim3(Mm / 128, CD / 128), 256, 0, stream>>>(memb, wkb, kbuf, nullptr, Mm, CD, CD);
  gemm128<1><<<dim3(Mm / 128, CD / 128), 256, 0, stream>>>(memb, wvb, vb,   nullptr, Mm, CD, CD);

  process_rows<<<Mq, 256, 0, stream>>>(q, sp);     // q -> bf16 in-place
  process_rows<<<Mm, 256, 0, stream>>>(kbuf, sp);  // k -> bf16 in-place

  const unsigned short* qb = (const unsigned short*)q;
  const unsigned short* kb = (const unsigned short*)kbuf;

  kv_part_k<<<dim3(24, KVCH), 256, 0, stream>>>(kb, vb, kvp, kmp);
  kv_reduce_k<<<30, 256, 0, stream>>>(kvp, kmp, kvT, km);

  dwconv_k<<<dim3(BSZ * NHEAD, 16), 256, 0, stream>>>(vb, dwc_w, dwc_b, dwcb);

  attn_mfma<<<dim3(BSZ * NHEAD, NX_ / 128), 256, 0, stream>>>(qb, kvT, km, dwcb, tmpb);

  gemm256c<0><<<dim3(Mq / 256, 4), 1024, 0, stream>>>(tmpb, wpb, out, b_proj, Mq, CD);
}